// Round 4
// baseline (266.093 us; speedup 1.0000x reference)
//
#include <hip/hip_runtime.h>
#include <hip/hip_bf16.h>
#include <math.h>

constexpr int NB   = 4;
constexpr int SEQ  = 2048;
constexpr int DM   = 1024;
constexpr int NH   = 16;
constexpr int DH2  = 64;
constexpr int NROWS = NB * SEQ; // 8192

typedef __attribute__((ext_vector_type(8))) short bf16x8;
typedef __attribute__((ext_vector_type(4))) short bf16x4;
typedef __attribute__((ext_vector_type(4))) float f32x4;

__device__ __forceinline__ unsigned short f2bf(float f) {
  __hip_bfloat16 h = __float2bfloat16(f);
  return *reinterpret_cast<unsigned short*>(&h);
}

__device__ __forceinline__ f32x4 mfma16(bf16x8 a, bf16x8 b, f32x4 c) {
  return __builtin_amdgcn_mfma_f32_16x16x32_bf16(a, b, c, 0, 0, 0);
}

// 16x16x16 bf16 MFMA via inline asm (A/B = 4 bf16 = 2 VGPR)
__device__ __forceinline__ f32x4 mfma16k16(bf16x4 a, bf16x4 b, f32x4 c) {
  asm("v_mfma_f32_16x16x16_bf16 %0, %1, %2, %0" : "+v"(c) : "v"(a), "v"(b));
  return c;
}

__device__ __forceinline__ void gload_lds16(const void* g, void* l) {
  __builtin_amdgcn_global_load_lds(
      (const __attribute__((address_space(1))) void*)g,
      (__attribute__((address_space(3))) void*)l, 16, 0, 0);
}

// ---------------- cast f32 -> bf16 ----------------
__global__ void cast_kernel(const float* __restrict__ in,
                            unsigned short* __restrict__ out, int n4) {
  int i = blockIdx.x * blockDim.x + threadIdx.x;
  int stride = gridDim.x * blockDim.x;
  for (int idx = i; idx < n4; idx += stride) {
    float4 v = reinterpret_cast<const float4*>(in)[idx];
    ushort4 o;
    o.x = f2bf(v.x); o.y = f2bf(v.y); o.z = f2bf(v.z); o.w = f2bf(v.w);
    reinterpret_cast<ushort4*>(out)[idx] = o;
  }
}

// ---------------- rope table ----------------
__global__ void rope_table_kernel(float2* __restrict__ tab, const int* __restrict__ pos) {
  int idx = blockIdx.x * blockDim.x + threadIdx.x;
  if (idx >= SEQ * 32) return;
  int s = idx >> 5, i = idx & 31;
  float inv = powf(10000.0f, -(float)i * (1.0f / 32.0f));
  float ang = (float)pos[s] * inv;
  tab[idx] = make_float2(cosf(ang), sinf(ang));
}

// ---------------- GEMM: C = A @ B^T (unchanged, known-good) ----------------
template<int MODE>
__global__ __launch_bounds__(256)
void gemm_bt(const unsigned short* __restrict__ Ag,
             const unsigned short* __restrict__ Bg,
             void* __restrict__ Cout,
             const float2* __restrict__ tab)
{
  constexpr int K = DM;
  __shared__ unsigned short As[128 * 32];
  __shared__ unsigned short Bs[128 * 32];
  const int tid = threadIdx.x;
  const int w = tid >> 6, lane = tid & 63;
  const int wr = w >> 1, wc = w & 1;
  const int r = lane & 15, g = lane >> 4;
  const int rowTile = blockIdx.x, colTile = blockIdx.y;
  const unsigned short* Abase = Ag + (size_t)rowTile * 128 * K;
  const unsigned short* Bbase = Bg + (size_t)colTile * 128 * K;

  f32x4 acc[4][4];
#pragma unroll
  for (int m = 0; m < 4; ++m)
#pragma unroll
    for (int n = 0; n < 4; ++n) acc[m][n] = f32x4{0.f, 0.f, 0.f, 0.f};

  const int e0 = w * 1024 + lane * 8;

  for (int k0 = 0; k0 < K; k0 += 32) {
#pragma unroll
    for (int c = 0; c < 2; ++c) {
      int e = e0 + c * 512;
      int trow = e >> 5, tcol = e & 31;
      gload_lds16(Abase + (size_t)trow * K + k0 + tcol, As + (w * 2 + c) * 512);
      gload_lds16(Bbase + (size_t)trow * K + k0 + tcol, Bs + (w * 2 + c) * 512);
    }
    __syncthreads();
    bf16x8 a[4], b[4];
#pragma unroll
    for (int m = 0; m < 4; ++m)
      a[m] = *reinterpret_cast<const bf16x8*>(As + (wr * 64 + m * 16 + r) * 32 + g * 8);
#pragma unroll
    for (int n = 0; n < 4; ++n)
      b[n] = *reinterpret_cast<const bf16x8*>(Bs + (wc * 64 + n * 16 + r) * 32 + g * 8);
#pragma unroll
    for (int m = 0; m < 4; ++m)
#pragma unroll
      for (int n = 0; n < 4; ++n)
        acc[m][n] = mfma16(a[m], b[n], acc[m][n]);
    __syncthreads();
  }

  const int row0 = rowTile * 128 + wr * 64;
  const int col0 = colTile * 128 + wc * 64;
  if constexpr (MODE == 0) {
    float* C = reinterpret_cast<float*>(Cout);
#pragma unroll
    for (int m = 0; m < 4; ++m)
#pragma unroll
      for (int n = 0; n < 4; ++n)
#pragma unroll
        for (int j = 0; j < 4; ++j) {
          int rr = row0 + m * 16 + g * 4 + j;
          int cc = col0 + n * 16 + r;
          C[(size_t)rr * DM + cc] = acc[m][n][j];
        }
  } else {
    unsigned short* Ob = reinterpret_cast<unsigned short*>(Cout);
#pragma unroll
    for (int m = 0; m < 4; ++m)
#pragma unroll
      for (int n = 0; n < 4; ++n)
#pragma unroll
        for (int j = 0; j < 4; ++j) {
          int rr = row0 + m * 16 + g * 4 + j;
          int ee = col0 + n * 16 + r;
          float val = acc[m][n][j];
          if constexpr (MODE == 1) {
            float partner = __shfl_xor(val, 1);
            int dd = ee & 63;
            int sr = rr & (SEQ - 1);
            float2 cs = tab[sr * 32 + (dd >> 1)];
            val = val * cs.x + (((ee & 1) == 0) ? -partner : partner) * cs.y;
          }
          int bb = rr >> 11;
          int sr2 = rr & (SEQ - 1);
          int h = ee >> 6, d = ee & 63;
          Ob[((size_t)(bb * NH + h) * SEQ + sr2) * DH2 + d] = f2bf(val);
        }
  }
}

// ---------------- flash attention v4: unpaired LPT grid, unroll-2 ping-pong ----
__global__ __launch_bounds__(256)
void flash_attn(const unsigned short* __restrict__ Qb,
                const unsigned short* __restrict__ Kb,
                const unsigned short* __restrict__ Vb,
                unsigned short* __restrict__ AO)
{
  constexpr int VST = 68;  // V^T lds row stride (shorts)
  __shared__ unsigned short Vt[2][64 * VST];
  const int tid = threadIdx.x;
  const int w = tid >> 6, lane = tid & 63;
  const int r = lane & 15, g = lane >> 4;
  const int qt = 15 - blockIdx.x;   // LPT: big q-tiles dispatch first (x fastest)
  const int bh = blockIdx.y;
  const unsigned short* Qh = Qb + (size_t)bh * SEQ * DH2;
  const unsigned short* Kh = Kb + (size_t)bh * SEQ * DH2;
  const unsigned short* Vh = Vb + (size_t)bh * SEQ * DH2;
  const int bb = bh >> 4, h = bh & 15;
  const int vd  = (lane & 7) * 8;
  const int vkv = w * 16 + (lane >> 3) * 2;
  const float C = 0.18033688f;      // 0.125 * log2(e)
  const float NEG_INF = -__builtin_inff();

  const int q0w = qt * 128 + w * 32;
  const int nT  = 2 * qt + 2;             // even
  const int myT = 2 * qt + 1 + (w >> 1);

  // Q fragments (B-operand of swapped QK): col=q0w+mq*16+r, k=kk*32+g*8
  bf16x8 qf[2][2];
#pragma unroll
  for (int mq = 0; mq < 2; ++mq)
#pragma unroll
    for (int kk = 0; kk < 2; ++kk)
      qf[mq][kk] = *reinterpret_cast<const bf16x8*>(
          Qh + (size_t)(q0w + mq * 16 + r) * DH2 + kk * 32 + g * 8);

  // K fragments (A-operand): row=kv0+nk*16+r, k=kk*32+g*8
  bf16x8 kA[2][4], kB[2][4];
#pragma unroll
  for (int kk = 0; kk < 2; ++kk)
#pragma unroll
    for (int nk = 0; nk < 4; ++nk)
      kA[kk][nk] = *reinterpret_cast<const bf16x8*>(
          Kh + (size_t)(nk * 16 + r) * DH2 + kk * 32 + g * 8);

  // stage V tile 0 as V^T
  {
    const uint4* p0 = reinterpret_cast<const uint4*>(Vh + (size_t)vkv * DH2 + vd);
    const uint4* p1 = reinterpret_cast<const uint4*>(Vh + (size_t)(vkv + 1) * DH2 + vd);
    uint4 a0 = *p0, a1 = *p1;
    const unsigned int* d0 = reinterpret_cast<const unsigned int*>(&a0);
    const unsigned int* d1 = reinterpret_cast<const unsigned int*>(&a1);
#pragma unroll
    for (int k2 = 0; k2 < 4; ++k2) {
      *reinterpret_cast<unsigned int*>(&Vt[0][(vd + 2 * k2) * VST + vkv]) =
          __builtin_amdgcn_perm(d1[k2], d0[k2], 0x05040100u);
      *reinterpret_cast<unsigned int*>(&Vt[0][(vd + 2 * k2 + 1) * VST + vkv]) =
          __builtin_amdgcn_perm(d1[k2], d0[k2], 0x07060302u);
    }
  }
  __syncthreads();

  f32x4 oacc[2][4];
  float m_run[2], l_part[2];
#pragma unroll
  for (int mq = 0; mq < 2; ++mq) {
#pragma unroll
    for (int nd = 0; nd < 4; ++nd) oacc[mq][nd] = f32x4{0.f, 0.f, 0.f, 0.f};
    m_run[mq] = NEG_INF;
    l_part[mq] = 0.f;
  }

  uint4 va0, va1;

  auto prefetchK = [&](int tile, bf16x8 (&kf)[2][4]) {
    const size_t kv0n = (size_t)tile * 64;
#pragma unroll
    for (int kk = 0; kk < 2; ++kk)
#pragma unroll
      for (int nk = 0; nk < 4; ++nk)
        kf[kk][nk] = *reinterpret_cast<const bf16x8*>(
            Kh + (kv0n + nk * 16 + r) * DH2 + kk * 32 + g * 8);
  };
  auto prefetchV = [&](int tile) {
    const size_t kv0n = (size_t)tile * 64;
    va0 = *reinterpret_cast<const uint4*>(Vh + (kv0n + vkv) * DH2 + vd);
    va1 = *reinterpret_cast<const uint4*>(Vh + (kv0n + vkv + 1) * DH2 + vd);
  };
  auto stageV = [&](int buf) {
    const unsigned int* d0 = reinterpret_cast<const unsigned int*>(&va0);
    const unsigned int* d1 = reinterpret_cast<const unsigned int*>(&va1);
#pragma unroll
    for (int k2 = 0; k2 < 4; ++k2) {
      *reinterpret_cast<unsigned int*>(&Vt[buf][(vd + 2 * k2) * VST + vkv]) =
          __builtin_amdgcn_perm(d1[k2], d0[k2], 0x05040100u);
      *reinterpret_cast<unsigned int*>(&Vt[buf][(vd + 2 * k2 + 1) * VST + vkv]) =
          __builtin_amdgcn_perm(d1[k2], d0[k2], 0x07060302u);
    }
  };

  auto computeTile = [&](int t, bf16x8 (&kf)[2][4], int cur) {
    const int kv0 = t * 64;
    f32x4 sacc[2][4];
#pragma unroll
    for (int mq = 0; mq < 2; ++mq)
#pragma unroll
      for (int nk = 0; nk < 4; ++nk) sacc[mq][nk] = f32x4{0.f, 0.f, 0.f, 0.f};
    __builtin_amdgcn_s_setprio(1);
#pragma unroll
    for (int kk = 0; kk < 2; ++kk)
#pragma unroll
      for (int mq = 0; mq < 2; ++mq)
#pragma unroll
        for (int nk = 0; nk < 4; ++nk)
          sacc[mq][nk] = mfma16(kf[kk][nk], qf[mq][kk], sacc[mq][nk]);
    __builtin_amdgcn_s_setprio(0);

    if (t == myT - 1) {   // causal mask on diagonal tile (raw scores)
#pragma unroll
      for (int mq = 0; mq < 2; ++mq) {
        const int qg = q0w + mq * 16 + r;
#pragma unroll
        for (int nk = 0; nk < 4; ++nk)
#pragma unroll
          for (int j = 0; j < 4; ++j) {
            int kg = kv0 + nk * 16 + g * 4 + j;
            if (kg > qg) sacc[mq][nk][j] = NEG_INF;
          }
      }
    }

    float vmax[2];
#pragma unroll
    for (int mq = 0; mq < 2; ++mq) {
      float v0 = fmaxf(fmaxf(sacc[mq][0][0], sacc[mq][0][1]),
                       fmaxf(sacc[mq][0][2], sacc[mq][0][3]));
      float v1 = fmaxf(fmaxf(sacc[mq][1][0], sacc[mq][1][1]),
                       fmaxf(sacc[mq][1][2], sacc[mq][1][3]));
      float v2 = fmaxf(fmaxf(sacc[mq][2][0], sacc[mq][2][1]),
                       fmaxf(sacc[mq][2][2], sacc[mq][2][3]));
      float v3 = fmaxf(fmaxf(sacc[mq][3][0], sacc[mq][3][1]),
                       fmaxf(sacc[mq][3][2], sacc[mq][3][3]));
      float v = fmaxf(fmaxf(v0, v1), fmaxf(v2, v3));
      v = fmaxf(v, __shfl_xor(v, 16));
      v = fmaxf(v, __shfl_xor(v, 32));
      vmax[mq] = v;
    }

    // defer-max: skip rescale when growth <= 64 raw (=8 in exp units)
    int cskip = (vmax[0] <= m_run[0] + 64.f) && (vmax[1] <= m_run[1] + 64.f);
    if (!__all(cskip)) {
#pragma unroll
      for (int mq = 0; mq < 2; ++mq) {
        float mo = m_run[mq];
        float mn = fmaxf(mo, vmax[mq]);
        float cr = __builtin_amdgcn_exp2f((mo - mn) * C);
        m_run[mq] = mn;
        l_part[mq] *= cr;
        float co[4];
#pragma unroll
        for (int j = 0; j < 4; ++j) co[j] = __shfl(cr, g * 4 + j);
#pragma unroll
        for (int nd = 0; nd < 4; ++nd)
#pragma unroll
          for (int j = 0; j < 4; ++j)
            oacc[mq][nd][j] *= co[j];
      }
    }

    bf16x4 pa[2][4];
#pragma unroll
    for (int mq = 0; mq < 2; ++mq) {
      float mC = m_run[mq] * C;
      float ls = 0.f;
#pragma unroll
      for (int nk = 0; nk < 4; ++nk) {
        float p0 = __builtin_amdgcn_exp2f(fmaf(sacc[mq][nk][0], C, -mC));
        float p1 = __builtin_amdgcn_exp2f(fmaf(sacc[mq][nk][1], C, -mC));
        float p2 = __builtin_amdgcn_exp2f(fmaf(sacc[mq][nk][2], C, -mC));
        float p3 = __builtin_amdgcn_exp2f(fmaf(sacc[mq][nk][3], C, -mC));
        ls += (p0 + p1) + (p2 + p3);
        pa[mq][nk] = bf16x4{(short)f2bf(p0), (short)f2bf(p1),
                            (short)f2bf(p2), (short)f2bf(p3)};
      }
      l_part[mq] += ls;
    }

    __builtin_amdgcn_s_setprio(1);
#pragma unroll
    for (int nd = 0; nd < 4; ++nd) {
      bf16x4 vb[4];
#pragma unroll
      for (int nk = 0; nk < 4; ++nk)
        vb[nk] = *reinterpret_cast<const bf16x4*>(
            &Vt[cur][(nd * 16 + r) * VST + nk * 16 + 4 * g]);
#pragma unroll
      for (int mq = 0; mq < 2; ++mq)
#pragma unroll
        for (int nk = 0; nk < 4; ++nk)
          oacc[mq][nd] = mfma16k16(pa[mq][nk], vb[nk], oacc[mq][nd]);
    }
    __builtin_amdgcn_s_setprio(0);
  };

  for (int t = 0; t < nT; t += 2) {
    // ---- iter A: tile t (V in Vt[0], K in kA) ----
    prefetchK((t + 1 < nT) ? t + 1 : nT - 1, kB);
    prefetchV((t + 1 < nT) ? t + 1 : nT - 1);
    if (t < myT) computeTile(t, kA, 0);
    stageV(1);
    __syncthreads();
    // ---- iter B: tile t+1 (V in Vt[1], K in kB) ----
    prefetchK((t + 2 < nT) ? t + 2 : nT - 1, kA);
    prefetchV((t + 2 < nT) ? t + 2 : nT - 1);
    if (t + 1 < myT) computeTile(t + 1, kB, 1);
    stageV(0);
    __syncthreads();
  }

  // epilogue: O rows q=mq*16+4g+j, cols d=nd*16+r
#pragma unroll
  for (int mq = 0; mq < 2; ++mq) {
    float l = l_part[mq];
    l += __shfl_xor(l, 16);
    l += __shfl_xor(l, 32);
#pragma unroll
    for (int j = 0; j < 4; ++j) {
      float inv = 1.0f / __shfl(l, g * 4 + j);
      int srow = q0w + mq * 16 + g * 4 + j;
#pragma unroll
      for (int nd = 0; nd < 4; ++nd) {
        int d = nd * 16 + r;
        AO[(size_t)(bb * SEQ + srow) * DM + h * DH2 + d] = f2bf(oacc[mq][nd][j] * inv);
      }
    }
  }
}

extern "C" void kernel_launch(void* const* d_in, const int* in_sizes, int n_in,
                              void* d_out, int out_size, void* d_ws, size_t ws_size,
                              hipStream_t stream) {
  const float* x  = (const float*)d_in[0];
  const float* WQ = (const float*)d_in[1];
  const float* WK = (const float*)d_in[2];
  const float* WV = (const float*)d_in[3];
  const float* WO = (const float*)d_in[4];
  const int* pos  = (const int*)d_in[5];

  char* ws = (char*)d_ws;
  unsigned short* xb  = (unsigned short*)(ws + 0);
  unsigned short* wqb = (unsigned short*)(ws + (16u << 20));
  unsigned short* wkb = (unsigned short*)(ws + (18u << 20));
  unsigned short* wvb = (unsigned short*)(ws + (20u << 20));
  unsigned short* wob = (unsigned short*)(ws + (22u << 20));
  unsigned short* Qb  = (unsigned short*)(ws + (24u << 20));
  unsigned short* Kb  = (unsigned short*)(ws + (40u << 20));
  unsigned short* Vb  = (unsigned short*)(ws + (56u << 20));
  unsigned short* AO  = (unsigned short*)(ws + (72u << 20));
  float2* tab = (float2*)(ws + (88u << 20));

  cast_kernel<<<2048, 256, 0, stream>>>(x, xb, NROWS * DM / 4);
  cast_kernel<<<256, 256, 0, stream>>>(WQ, wqb, DM * DM / 4);
  cast_kernel<<<256, 256, 0, stream>>>(WK, wkb, DM * DM / 4);
  cast_kernel<<<256, 256, 0, stream>>>(WV, wvb, DM * DM / 4);
  cast_kernel<<<256, 256, 0, stream>>>(WO, wob, DM * DM / 4);
  rope_table_kernel<<<(SEQ * 32 + 255) / 256, 256, 0, stream>>>(tab, pos);

  dim3 gproj(NROWS / 128, DM / 128);
  gemm_bt<1><<<gproj, 256, 0, stream>>>(xb, wqb, (void*)Qb, tab);
  gemm_bt<1><<<gproj, 256, 0, stream>>>(xb, wkb, (void*)Kb, tab);
  gemm_bt<2><<<gproj, 256, 0, stream>>>(xb, wvb, (void*)Vb, nullptr);
  flash_attn<<<dim3(16, NB * NH), 256, 0, stream>>>(Qb, Kb, Vb, AO);
  gemm_bt<0><<<gproj, 256, 0, stream>>>(AO, wob, d_out, nullptr);
}

// Round 5
// 244.576 us; speedup vs baseline: 1.0880x; 1.0880x over previous
//
#include <hip/hip_runtime.h>
#include <hip/hip_bf16.h>
#include <math.h>

constexpr int NB   = 4;
constexpr int SEQ  = 2048;
constexpr int DM   = 1024;
constexpr int NH   = 16;
constexpr int DH2  = 64;
constexpr int NROWS = NB * SEQ; // 8192

typedef __attribute__((ext_vector_type(8))) short bf16x8;
typedef __attribute__((ext_vector_type(4))) short bf16x4;
typedef __attribute__((ext_vector_type(4))) float f32x4;

__device__ __forceinline__ unsigned short f2bf(float f) {
  __hip_bfloat16 h = __float2bfloat16(f);
  return *reinterpret_cast<unsigned short*>(&h);
}

__device__ __forceinline__ f32x4 mfma16(bf16x8 a, bf16x8 b, f32x4 c) {
  return __builtin_amdgcn_mfma_f32_16x16x32_bf16(a, b, c, 0, 0, 0);
}

// 16x16x16 bf16 MFMA via inline asm (A/B = 4 bf16 = 2 VGPR)
__device__ __forceinline__ f32x4 mfma16k16(bf16x4 a, bf16x4 b, f32x4 c) {
  asm("v_mfma_f32_16x16x16_bf16 %0, %1, %2, %0" : "+v"(c) : "v"(a), "v"(b));
  return c;
}

__device__ __forceinline__ void gload_lds16(const void* g, void* l) {
  __builtin_amdgcn_global_load_lds(
      (const __attribute__((address_space(1))) void*)g,
      (__attribute__((address_space(3))) void*)l, 16, 0, 0);
}

// ---------------- cast f32 -> bf16 ----------------
__global__ void cast_kernel(const float* __restrict__ in,
                            unsigned short* __restrict__ out, int n4) {
  int i = blockIdx.x * blockDim.x + threadIdx.x;
  int stride = gridDim.x * blockDim.x;
  for (int idx = i; idx < n4; idx += stride) {
    float4 v = reinterpret_cast<const float4*>(in)[idx];
    ushort4 o;
    o.x = f2bf(v.x); o.y = f2bf(v.y); o.z = f2bf(v.z); o.w = f2bf(v.w);
    reinterpret_cast<ushort4*>(out)[idx] = o;
  }
}

// ---------------- rope table ----------------
__global__ void rope_table_kernel(float2* __restrict__ tab, const int* __restrict__ pos) {
  int idx = blockIdx.x * blockDim.x + threadIdx.x;
  if (idx >= SEQ * 32) return;
  int s = idx >> 5, i = idx & 31;
  float inv = powf(10000.0f, -(float)i * (1.0f / 32.0f));
  float ang = (float)pos[s] * inv;
  tab[idx] = make_float2(cosf(ang), sinf(ang));
}

// ---------------- GEMM: C = A @ B^T (unchanged, known-good) ----------------
template<int MODE>
__global__ __launch_bounds__(256)
void gemm_bt(const unsigned short* __restrict__ Ag,
             const unsigned short* __restrict__ Bg,
             void* __restrict__ Cout,
             const float2* __restrict__ tab)
{
  constexpr int K = DM;
  __shared__ unsigned short As[128 * 32];
  __shared__ unsigned short Bs[128 * 32];
  const int tid = threadIdx.x;
  const int w = tid >> 6, lane = tid & 63;
  const int wr = w >> 1, wc = w & 1;
  const int r = lane & 15, g = lane >> 4;
  const int rowTile = blockIdx.x, colTile = blockIdx.y;
  const unsigned short* Abase = Ag + (size_t)rowTile * 128 * K;
  const unsigned short* Bbase = Bg + (size_t)colTile * 128 * K;

  f32x4 acc[4][4];
#pragma unroll
  for (int m = 0; m < 4; ++m)
#pragma unroll
    for (int n = 0; n < 4; ++n) acc[m][n] = f32x4{0.f, 0.f, 0.f, 0.f};

  const int e0 = w * 1024 + lane * 8;

  for (int k0 = 0; k0 < K; k0 += 32) {
#pragma unroll
    for (int c = 0; c < 2; ++c) {
      int e = e0 + c * 512;
      int trow = e >> 5, tcol = e & 31;
      gload_lds16(Abase + (size_t)trow * K + k0 + tcol, As + (w * 2 + c) * 512);
      gload_lds16(Bbase + (size_t)trow * K + k0 + tcol, Bs + (w * 2 + c) * 512);
    }
    __syncthreads();
    bf16x8 a[4], b[4];
#pragma unroll
    for (int m = 0; m < 4; ++m)
      a[m] = *reinterpret_cast<const bf16x8*>(As + (wr * 64 + m * 16 + r) * 32 + g * 8);
#pragma unroll
    for (int n = 0; n < 4; ++n)
      b[n] = *reinterpret_cast<const bf16x8*>(Bs + (wc * 64 + n * 16 + r) * 32 + g * 8);
#pragma unroll
    for (int m = 0; m < 4; ++m)
#pragma unroll
      for (int n = 0; n < 4; ++n)
        acc[m][n] = mfma16(a[m], b[n], acc[m][n]);
    __syncthreads();
  }

  const int row0 = rowTile * 128 + wr * 64;
  const int col0 = colTile * 128 + wc * 64;
  if constexpr (MODE == 0) {
    float* C = reinterpret_cast<float*>(Cout);
#pragma unroll
    for (int m = 0; m < 4; ++m)
#pragma unroll
      for (int n = 0; n < 4; ++n)
#pragma unroll
        for (int j = 0; j < 4; ++j) {
          int rr = row0 + m * 16 + g * 4 + j;
          int cc = col0 + n * 16 + r;
          C[(size_t)rr * DM + cc] = acc[m][n][j];
        }
  } else {
    unsigned short* Ob = reinterpret_cast<unsigned short*>(Cout);
#pragma unroll
    for (int m = 0; m < 4; ++m)
#pragma unroll
      for (int n = 0; n < 4; ++n)
#pragma unroll
        for (int j = 0; j < 4; ++j) {
          int rr = row0 + m * 16 + g * 4 + j;
          int ee = col0 + n * 16 + r;
          float val = acc[m][n][j];
          if constexpr (MODE == 1) {
            float partner = __shfl_xor(val, 1);
            int dd = ee & 63;
            int sr = rr & (SEQ - 1);
            float2 cs = tab[sr * 32 + (dd >> 1)];
            val = val * cs.x + (((ee & 1) == 0) ? -partner : partner) * cs.y;
          }
          int bb = rr >> 11;
          int sr2 = rr & (SEQ - 1);
          int h = ee >> 6, d = ee & 63;
          Ob[((size_t)(bb * NH + h) * SEQ + sr2) * DH2 + d] = f2bf(val);
        }
  }
}

// ---------------- flash attention v5: paired balanced grid + cheap VALU ----
__global__ __launch_bounds__(256)
void flash_attn(const unsigned short* __restrict__ Qb,
                const unsigned short* __restrict__ Kb,
                const unsigned short* __restrict__ Vb,
                unsigned short* __restrict__ AO)
{
  constexpr int VST = 68;  // V^T lds row stride (shorts)
  __shared__ unsigned short Vt[2][64 * VST];
  const int tid = threadIdx.x;
  const int w = tid >> 6, lane = tid & 63;
  const int r = lane & 15, g = lane >> 4;
  const int pr = blockIdx.x;        // pair index 0..7
  const int bh = blockIdx.y;
  const unsigned short* Qh = Qb + (size_t)bh * SEQ * DH2;
  const unsigned short* Kh = Kb + (size_t)bh * SEQ * DH2;
  const unsigned short* Vh = Vb + (size_t)bh * SEQ * DH2;
  const int bb = bh >> 4, h = bh & 15;
  const int vd  = (lane & 7) * 8;
  const int vkv = w * 16 + (lane >> 3) * 2;
  const float C = 0.18033688f;      // 0.125 * log2(e)
  const float NEG_INF = -__builtin_inff();

  for (int ctx = 0; ctx < 2; ++ctx) {
    const int qt = ctx ? pr : (15 - pr);   // big tile first; pair sums to 34 tiles
    const int q0w = qt * 128 + w * 32;
    const int nT  = 2 * qt + 2;             // even
    const int myT = 2 * qt + 1 + (w >> 1);

    // Q fragments (B-operand of swapped QK): col=q0w+mq*16+r, k=kk*32+g*8
    bf16x8 qf[2][2];
#pragma unroll
    for (int mq = 0; mq < 2; ++mq)
#pragma unroll
      for (int kk = 0; kk < 2; ++kk)
        qf[mq][kk] = *reinterpret_cast<const bf16x8*>(
            Qh + (size_t)(q0w + mq * 16 + r) * DH2 + kk * 32 + g * 8);

    // K fragments (A-operand): row=kv0+nk*16+r, k=kk*32+g*8
    bf16x8 kA[2][4], kB[2][4];
#pragma unroll
    for (int kk = 0; kk < 2; ++kk)
#pragma unroll
      for (int nk = 0; nk < 4; ++nk)
        kA[kk][nk] = *reinterpret_cast<const bf16x8*>(
            Kh + (size_t)(nk * 16 + r) * DH2 + kk * 32 + g * 8);

    // stage V tile 0 as V^T
    {
      uint4 a0 = *reinterpret_cast<const uint4*>(Vh + (size_t)vkv * DH2 + vd);
      uint4 a1 = *reinterpret_cast<const uint4*>(Vh + (size_t)(vkv + 1) * DH2 + vd);
      const unsigned int* d0 = reinterpret_cast<const unsigned int*>(&a0);
      const unsigned int* d1 = reinterpret_cast<const unsigned int*>(&a1);
#pragma unroll
      for (int k2 = 0; k2 < 4; ++k2) {
        *reinterpret_cast<unsigned int*>(&Vt[0][(vd + 2 * k2) * VST + vkv]) =
            __builtin_amdgcn_perm(d1[k2], d0[k2], 0x05040100u);
        *reinterpret_cast<unsigned int*>(&Vt[0][(vd + 2 * k2 + 1) * VST + vkv]) =
            __builtin_amdgcn_perm(d1[k2], d0[k2], 0x07060302u);
      }
    }
    __syncthreads();

    f32x4 oacc[2][4];
    float m_run[2], l_part[2];
#pragma unroll
    for (int mq = 0; mq < 2; ++mq) {
#pragma unroll
      for (int nd = 0; nd < 4; ++nd) oacc[mq][nd] = f32x4{0.f, 0.f, 0.f, 0.f};
      m_run[mq] = NEG_INF;
      l_part[mq] = 0.f;
    }

    uint4 va0, va1;

    auto prefetchK = [&](int tile, bf16x8 (&kf)[2][4]) {
      const size_t kv0n = (size_t)tile * 64;
#pragma unroll
      for (int kk = 0; kk < 2; ++kk)
#pragma unroll
        for (int nk = 0; nk < 4; ++nk)
          kf[kk][nk] = *reinterpret_cast<const bf16x8*>(
              Kh + (kv0n + nk * 16 + r) * DH2 + kk * 32 + g * 8);
    };
    auto prefetchV = [&](int tile) {
      const size_t kv0n = (size_t)tile * 64;
      va0 = *reinterpret_cast<const uint4*>(Vh + (kv0n + vkv) * DH2 + vd);
      va1 = *reinterpret_cast<const uint4*>(Vh + (kv0n + vkv + 1) * DH2 + vd);
    };
    auto stageV = [&](int buf) {
      const unsigned int* d0 = reinterpret_cast<const unsigned int*>(&va0);
      const unsigned int* d1 = reinterpret_cast<const unsigned int*>(&va1);
#pragma unroll
      for (int k2 = 0; k2 < 4; ++k2) {
        *reinterpret_cast<unsigned int*>(&Vt[buf][(vd + 2 * k2) * VST + vkv]) =
            __builtin_amdgcn_perm(d1[k2], d0[k2], 0x05040100u);
        *reinterpret_cast<unsigned int*>(&Vt[buf][(vd + 2 * k2 + 1) * VST + vkv]) =
            __builtin_amdgcn_perm(d1[k2], d0[k2], 0x07060302u);
      }
    };

    auto computeTile = [&](int t, bf16x8 (&kf)[2][4], int cur) {
      const int kv0 = t * 64;
      f32x4 sacc[2][4];
#pragma unroll
      for (int mq = 0; mq < 2; ++mq)
#pragma unroll
        for (int nk = 0; nk < 4; ++nk) sacc[mq][nk] = f32x4{0.f, 0.f, 0.f, 0.f};
      __builtin_amdgcn_s_setprio(1);
#pragma unroll
      for (int kk = 0; kk < 2; ++kk)
#pragma unroll
        for (int mq = 0; mq < 2; ++mq)
#pragma unroll
          for (int nk = 0; nk < 4; ++nk)
            sacc[mq][nk] = mfma16(kf[kk][nk], qf[mq][kk], sacc[mq][nk]);
      __builtin_amdgcn_s_setprio(0);

      if (t == myT - 1) {   // causal mask on diagonal tile (raw scores)
#pragma unroll
        for (int mq = 0; mq < 2; ++mq) {
          const int qg = q0w + mq * 16 + r;
#pragma unroll
          for (int nk = 0; nk < 4; ++nk)
#pragma unroll
            for (int j = 0; j < 4; ++j) {
              int kg = kv0 + nk * 16 + g * 4 + j;
              if (kg > qg) sacc[mq][nk][j] = NEG_INF;
            }
        }
      }

      float vmax[2];
#pragma unroll
      for (int mq = 0; mq < 2; ++mq) {
        float v0 = fmaxf(fmaxf(sacc[mq][0][0], sacc[mq][0][1]),
                         fmaxf(sacc[mq][0][2], sacc[mq][0][3]));
        float v1 = fmaxf(fmaxf(sacc[mq][1][0], sacc[mq][1][1]),
                         fmaxf(sacc[mq][1][2], sacc[mq][1][3]));
        float v2 = fmaxf(fmaxf(sacc[mq][2][0], sacc[mq][2][1]),
                         fmaxf(sacc[mq][2][2], sacc[mq][2][3]));
        float v3 = fmaxf(fmaxf(sacc[mq][3][0], sacc[mq][3][1]),
                         fmaxf(sacc[mq][3][2], sacc[mq][3][3]));
        float v = fmaxf(fmaxf(v0, v1), fmaxf(v2, v3));
        v = fmaxf(v, __shfl_xor(v, 16));
        v = fmaxf(v, __shfl_xor(v, 32));
        vmax[mq] = v;
      }

      // defer-max: skip rescale when growth <= 64 raw (=8 in exp units)
      int cskip = (vmax[0] <= m_run[0] + 64.f) && (vmax[1] <= m_run[1] + 64.f);
      if (!__all(cskip)) {
#pragma unroll
        for (int mq = 0; mq < 2; ++mq) {
          float mo = m_run[mq];
          float mn = fmaxf(mo, vmax[mq]);
          float cr = __builtin_amdgcn_exp2f((mo - mn) * C);
          m_run[mq] = mn;
          l_part[mq] *= cr;
          float co[4];
#pragma unroll
          for (int j = 0; j < 4; ++j) co[j] = __shfl(cr, g * 4 + j);
#pragma unroll
          for (int nd = 0; nd < 4; ++nd)
#pragma unroll
            for (int j = 0; j < 4; ++j)
              oacc[mq][nd][j] *= co[j];
        }
      }

      bf16x4 pa[2][4];
#pragma unroll
      for (int mq = 0; mq < 2; ++mq) {
        float mC = m_run[mq] * C;
        float ls = 0.f;
#pragma unroll
        for (int nk = 0; nk < 4; ++nk) {
          float p0 = __builtin_amdgcn_exp2f(fmaf(sacc[mq][nk][0], C, -mC));
          float p1 = __builtin_amdgcn_exp2f(fmaf(sacc[mq][nk][1], C, -mC));
          float p2 = __builtin_amdgcn_exp2f(fmaf(sacc[mq][nk][2], C, -mC));
          float p3 = __builtin_amdgcn_exp2f(fmaf(sacc[mq][nk][3], C, -mC));
          ls += (p0 + p1) + (p2 + p3);
          pa[mq][nk] = bf16x4{(short)f2bf(p0), (short)f2bf(p1),
                              (short)f2bf(p2), (short)f2bf(p3)};
        }
        l_part[mq] += ls;
      }

      __builtin_amdgcn_s_setprio(1);
#pragma unroll
      for (int nd = 0; nd < 4; ++nd) {
        bf16x4 vb[4];
#pragma unroll
        for (int nk = 0; nk < 4; ++nk)
          vb[nk] = *reinterpret_cast<const bf16x4*>(
              &Vt[cur][(nd * 16 + r) * VST + nk * 16 + 4 * g]);
#pragma unroll
        for (int mq = 0; mq < 2; ++mq)
#pragma unroll
          for (int nk = 0; nk < 4; ++nk)
            oacc[mq][nd] = mfma16k16(pa[mq][nk], vb[nk], oacc[mq][nd]);
      }
      __builtin_amdgcn_s_setprio(0);
    };

    for (int t = 0; t < nT; t += 2) {
      // ---- iter A: tile t (V in Vt[0], K in kA) ----
      prefetchK((t + 1 < nT) ? t + 1 : nT - 1, kB);
      prefetchV((t + 1 < nT) ? t + 1 : nT - 1);
      if (t < myT) computeTile(t, kA, 0);
      stageV(1);
      __syncthreads();
      // ---- iter B: tile t+1 (V in Vt[1], K in kB) ----
      prefetchK((t + 2 < nT) ? t + 2 : nT - 1, kA);
      prefetchV((t + 2 < nT) ? t + 2 : nT - 1);
      if (t + 1 < myT) computeTile(t + 1, kB, 1);
      stageV(0);
      __syncthreads();
    }

    // epilogue: O rows q=mq*16+4g+j, cols d=nd*16+r
#pragma unroll
    for (int mq = 0; mq < 2; ++mq) {
      float l = l_part[mq];
      l += __shfl_xor(l, 16);
      l += __shfl_xor(l, 32);
#pragma unroll
      for (int j = 0; j < 4; ++j) {
        float inv = 1.0f / __shfl(l, g * 4 + j);
        int srow = q0w + mq * 16 + g * 4 + j;
#pragma unroll
        for (int nd = 0; nd < 4; ++nd) {
          int d = nd * 16 + r;
          AO[(size_t)(bb * SEQ + srow) * DM + h * DH2 + d] = f2bf(oacc[mq][nd][j] * inv);
        }
      }
    }
  }
}

extern "C" void kernel_launch(void* const* d_in, const int* in_sizes, int n_in,
                              void* d_out, int out_size, void* d_ws, size_t ws_size,
                              hipStream_t stream) {
  const float* x  = (const float*)d_in[0];
  const float* WQ = (const float*)d_in[1];
  const float* WK = (const float*)d_in[2];
  const float* WV = (const float*)d_in[3];
  const float* WO = (const float*)d_in[4];
  const int* pos  = (const int*)d_in[5];

  char* ws = (char*)d_ws;
  unsigned short* xb  = (unsigned short*)(ws + 0);
  unsigned short* wqb = (unsigned short*)(ws + (16u << 20));
  unsigned short* wkb = (unsigned short*)(ws + (18u << 20));
  unsigned short* wvb = (unsigned short*)(ws + (20u << 20));
  unsigned short* wob = (unsigned short*)(ws + (22u << 20));
  unsigned short* Qb  = (unsigned short*)(ws + (24u << 20));
  unsigned short* Kb  = (unsigned short*)(ws + (40u << 20));
  unsigned short* Vb  = (unsigned short*)(ws + (56u << 20));
  unsigned short* AO  = (unsigned short*)(ws + (72u << 20));
  float2* tab = (float2*)(ws + (88u << 20));

  cast_kernel<<<2048, 256, 0, stream>>>(x, xb, NROWS * DM / 4);
  cast_kernel<<<256, 256, 0, stream>>>(WQ, wqb, DM * DM / 4);
  cast_kernel<<<256, 256, 0, stream>>>(WK, wkb, DM * DM / 4);
  cast_kernel<<<256, 256, 0, stream>>>(WV, wvb, DM * DM / 4);
  cast_kernel<<<256, 256, 0, stream>>>(WO, wob, DM * DM / 4);
  rope_table_kernel<<<(SEQ * 32 + 255) / 256, 256, 0, stream>>>(tab, pos);

  dim3 gproj(NROWS / 128, DM / 128);
  gemm_bt<1><<<gproj, 256, 0, stream>>>(xb, wqb, (void*)Qb, tab);
  gemm_bt<1><<<gproj, 256, 0, stream>>>(xb, wkb, (void*)Kb, tab);
  gemm_bt<2><<<gproj, 256, 0, stream>>>(xb, wvb, (void*)Vb, nullptr);
  flash_attn<<<dim3(8, NB * NH), 256, 0, stream>>>(Qb, Kb, Vb, AO);
  gemm_bt<0><<<gproj, 256, 0, stream>>>(AO, wob, d_out, nullptr);
}

// Round 6
// 231.267 us; speedup vs baseline: 1.1506x; 1.0575x over previous
//
#include <hip/hip_runtime.h>
#include <hip/hip_bf16.h>
#include <math.h>

constexpr int NB   = 4;
constexpr int SEQ  = 2048;
constexpr int DM   = 1024;
constexpr int NH   = 16;
constexpr int DH2  = 64;
constexpr int NROWS = NB * SEQ; // 8192

typedef __attribute__((ext_vector_type(8))) short bf16x8;
typedef __attribute__((ext_vector_type(4))) short bf16x4;
typedef __attribute__((ext_vector_type(4))) float f32x4;

__device__ __forceinline__ unsigned short f2bf(float f) {
  __hip_bfloat16 h = __float2bfloat16(f);
  return *reinterpret_cast<unsigned short*>(&h);
}

__device__ __forceinline__ f32x4 mfma16(bf16x8 a, bf16x8 b, f32x4 c) {
  return __builtin_amdgcn_mfma_f32_16x16x32_bf16(a, b, c, 0, 0, 0);
}

// 16x16x16 bf16 MFMA via inline asm (A/B = 4 bf16 = 2 VGPR)
__device__ __forceinline__ f32x4 mfma16k16(bf16x4 a, bf16x4 b, f32x4 c) {
  asm("v_mfma_f32_16x16x16_bf16 %0, %1, %2, %0" : "+v"(c) : "v"(a), "v"(b));
  return c;
}

__device__ __forceinline__ void gload_lds16(const void* g, void* l) {
  __builtin_amdgcn_global_load_lds(
      (const __attribute__((address_space(1))) void*)g,
      (__attribute__((address_space(3))) void*)l, 16, 0, 0);
}

// ---------------- cast f32 -> bf16 ----------------
__global__ void cast_kernel(const float* __restrict__ in,
                            unsigned short* __restrict__ out, int n4) {
  int i = blockIdx.x * blockDim.x + threadIdx.x;
  int stride = gridDim.x * blockDim.x;
  for (int idx = i; idx < n4; idx += stride) {
    float4 v = reinterpret_cast<const float4*>(in)[idx];
    ushort4 o;
    o.x = f2bf(v.x); o.y = f2bf(v.y); o.z = f2bf(v.z); o.w = f2bf(v.w);
    reinterpret_cast<ushort4*>(out)[idx] = o;
  }
}

// ---------------- rope table ----------------
__global__ void rope_table_kernel(float2* __restrict__ tab, const int* __restrict__ pos) {
  int idx = blockIdx.x * blockDim.x + threadIdx.x;
  if (idx >= SEQ * 32) return;
  int s = idx >> 5, i = idx & 31;
  float inv = powf(10000.0f, -(float)i * (1.0f / 32.0f));
  float ang = (float)pos[s] * inv;
  tab[idx] = make_float2(cosf(ang), sinf(ang));
}

// ---------------- fused QKV GEMM: colTile 0..23 spans [WQ|WK|WV] (contiguous) ----
__global__ __launch_bounds__(256)
void gemm_qkv(const unsigned short* __restrict__ Ag,
              const unsigned short* __restrict__ Bg,   // wqb (wk, wv follow contiguously)
              unsigned short* __restrict__ Qb,
              unsigned short* __restrict__ Kb,
              unsigned short* __restrict__ Vb,
              const float2* __restrict__ tab)
{
  constexpr int K = DM;
  __shared__ unsigned short As[128 * 32];
  __shared__ unsigned short Bs[128 * 32];
  const int tid = threadIdx.x;
  const int w = tid >> 6, lane = tid & 63;
  const int wr = w >> 1, wc = w & 1;
  const int r = lane & 15, g = lane >> 4;
  const int rowTile = blockIdx.x, colTile = blockIdx.y;
  const unsigned short* Abase = Ag + (size_t)rowTile * 128 * K;
  const unsigned short* Bbase = Bg + (size_t)colTile * 128 * K;

  f32x4 acc[4][4];
#pragma unroll
  for (int m = 0; m < 4; ++m)
#pragma unroll
    for (int n = 0; n < 4; ++n) acc[m][n] = f32x4{0.f, 0.f, 0.f, 0.f};

  const int e0 = w * 1024 + lane * 8;

  for (int k0 = 0; k0 < K; k0 += 32) {
#pragma unroll
    for (int c = 0; c < 2; ++c) {
      int e = e0 + c * 512;
      int trow = e >> 5, tcol = e & 31;
      gload_lds16(Abase + (size_t)trow * K + k0 + tcol, As + (w * 2 + c) * 512);
      gload_lds16(Bbase + (size_t)trow * K + k0 + tcol, Bs + (w * 2 + c) * 512);
    }
    __syncthreads();
    bf16x8 a[4], b[4];
#pragma unroll
    for (int m = 0; m < 4; ++m)
      a[m] = *reinterpret_cast<const bf16x8*>(As + (wr * 64 + m * 16 + r) * 32 + g * 8);
#pragma unroll
    for (int n = 0; n < 4; ++n)
      b[n] = *reinterpret_cast<const bf16x8*>(Bs + (wc * 64 + n * 16 + r) * 32 + g * 8);
#pragma unroll
    for (int m = 0; m < 4; ++m)
#pragma unroll
      for (int n = 0; n < 4; ++n)
        acc[m][n] = mfma16(a[m], b[n], acc[m][n]);
    __syncthreads();
  }

  const int which = colTile >> 3;
  unsigned short* Ob = (which == 0) ? Qb : (which == 1) ? Kb : Vb;
  const bool doRope = (which < 2);
  const int row0 = rowTile * 128 + wr * 64;
  const int col0 = (colTile & 7) * 128 + wc * 64;
#pragma unroll
  for (int m = 0; m < 4; ++m)
#pragma unroll
    for (int n = 0; n < 4; ++n)
#pragma unroll
      for (int j = 0; j < 4; ++j) {
        int rr = row0 + m * 16 + g * 4 + j;
        int ee = col0 + n * 16 + r;
        float val = acc[m][n][j];
        if (doRope) {
          float partner = __shfl_xor(val, 1);
          int dd = ee & 63;
          int sr = rr & (SEQ - 1);
          float2 cs = tab[sr * 32 + (dd >> 1)];
          val = val * cs.x + (((ee & 1) == 0) ? -partner : partner) * cs.y;
        }
        int bb = rr >> 11;
        int sr2 = rr & (SEQ - 1);
        int h = ee >> 6, d = ee & 63;
        Ob[((size_t)(bb * NH + h) * SEQ + sr2) * DH2 + d] = f2bf(val);
      }
}

// ---------------- output GEMM: C = A @ B^T, f32 out ----------------
__global__ __launch_bounds__(256)
void gemm_bt0(const unsigned short* __restrict__ Ag,
              const unsigned short* __restrict__ Bg,
              float* __restrict__ C)
{
  constexpr int K = DM;
  __shared__ unsigned short As[128 * 32];
  __shared__ unsigned short Bs[128 * 32];
  const int tid = threadIdx.x;
  const int w = tid >> 6, lane = tid & 63;
  const int wr = w >> 1, wc = w & 1;
  const int r = lane & 15, g = lane >> 4;
  const int rowTile = blockIdx.x, colTile = blockIdx.y;
  const unsigned short* Abase = Ag + (size_t)rowTile * 128 * K;
  const unsigned short* Bbase = Bg + (size_t)colTile * 128 * K;

  f32x4 acc[4][4];
#pragma unroll
  for (int m = 0; m < 4; ++m)
#pragma unroll
    for (int n = 0; n < 4; ++n) acc[m][n] = f32x4{0.f, 0.f, 0.f, 0.f};

  const int e0 = w * 1024 + lane * 8;

  for (int k0 = 0; k0 < K; k0 += 32) {
#pragma unroll
    for (int c = 0; c < 2; ++c) {
      int e = e0 + c * 512;
      int trow = e >> 5, tcol = e & 31;
      gload_lds16(Abase + (size_t)trow * K + k0 + tcol, As + (w * 2 + c) * 512);
      gload_lds16(Bbase + (size_t)trow * K + k0 + tcol, Bs + (w * 2 + c) * 512);
    }
    __syncthreads();
    bf16x8 a[4], b[4];
#pragma unroll
    for (int m = 0; m < 4; ++m)
      a[m] = *reinterpret_cast<const bf16x8*>(As + (wr * 64 + m * 16 + r) * 32 + g * 8);
#pragma unroll
    for (int n = 0; n < 4; ++n)
      b[n] = *reinterpret_cast<const bf16x8*>(Bs + (wc * 64 + n * 16 + r) * 32 + g * 8);
#pragma unroll
    for (int m = 0; m < 4; ++m)
#pragma unroll
      for (int n = 0; n < 4; ++n)
        acc[m][n] = mfma16(a[m], b[n], acc[m][n]);
    __syncthreads();
  }

  const int row0 = rowTile * 128 + wr * 64;
  const int col0 = colTile * 128 + wc * 64;
#pragma unroll
  for (int m = 0; m < 4; ++m)
#pragma unroll
    for (int n = 0; n < 4; ++n)
#pragma unroll
      for (int j = 0; j < 4; ++j) {
        int rr = row0 + m * 16 + g * 4 + j;
        int cc = col0 + n * 16 + r;
        C[(size_t)rr * DM + cc] = acc[m][n][j];
      }
}

// ---------------- flash attention v6: R3 structure + fixed-max softmax ----------
__global__ __launch_bounds__(256)
void flash_attn(const unsigned short* __restrict__ Qb,
                const unsigned short* __restrict__ Kb,
                const unsigned short* __restrict__ Vb,
                unsigned short* __restrict__ AO)
{
  constexpr int VST = 68;  // V^T lds row stride (shorts)
  __shared__ unsigned short Vt[2][64 * VST];
  const int tid = threadIdx.x;
  const int w = tid >> 6, lane = tid & 63;
  const int r = lane & 15, g = lane >> 4;
  const int pr = blockIdx.x;        // pair index 0..7
  const int bh = blockIdx.y;
  const unsigned short* Qh = Qb + (size_t)bh * SEQ * DH2;
  const unsigned short* Kh = Kb + (size_t)bh * SEQ * DH2;
  const unsigned short* Vh = Vb + (size_t)bh * SEQ * DH2;
  const int bb = bh >> 4, h = bh & 15;
  const int vd  = (lane & 7) * 8;
  const int vkv = w * 16 + (lane >> 3) * 2;
  const float C = 0.18033688f;        // 0.125 * log2(e)
  const float M0 = 11.5415603f;       // 8 * log2(e): fixed max shift (exact softmax, shifted)
  const float NEG_INF = -__builtin_inff();

  for (int ctx = 0; ctx < 2; ++ctx) {
    const int qt = ctx ? pr : (15 - pr);   // big tile first; pair sums to 34 tiles
    const int q0w = qt * 128 + w * 32;
    const int nT  = 2 * qt + 2;
    const int myT = 2 * qt + 1 + (w >> 1);

    // Q fragments (B-operand of swapped QK): col=q0w+mq*16+r, k=kk*32+g*8
    bf16x8 qf[2][2];
#pragma unroll
    for (int mq = 0; mq < 2; ++mq)
#pragma unroll
      for (int kk = 0; kk < 2; ++kk)
        qf[mq][kk] = *reinterpret_cast<const bf16x8*>(
            Qh + (size_t)(q0w + mq * 16 + r) * DH2 + kk * 32 + g * 8);

    // K fragments (A-operand): row=kv0+nk*16+r, k=kk*32+g*8
    bf16x8 kc[2][4], kn[2][4];
#pragma unroll
    for (int kk = 0; kk < 2; ++kk)
#pragma unroll
      for (int nk = 0; nk < 4; ++nk)
        kc[kk][nk] = *reinterpret_cast<const bf16x8*>(
            Kh + (size_t)(nk * 16 + r) * DH2 + kk * 32 + g * 8);

    // stage V tile 0 as V^T (perm pack)
    {
      uint4 a0 = *reinterpret_cast<const uint4*>(Vh + (size_t)vkv * DH2 + vd);
      uint4 a1 = *reinterpret_cast<const uint4*>(Vh + (size_t)(vkv + 1) * DH2 + vd);
      const unsigned int* d0 = reinterpret_cast<const unsigned int*>(&a0);
      const unsigned int* d1 = reinterpret_cast<const unsigned int*>(&a1);
#pragma unroll
      for (int k2 = 0; k2 < 4; ++k2) {
        *reinterpret_cast<unsigned int*>(&Vt[0][(vd + 2 * k2) * VST + vkv]) =
            __builtin_amdgcn_perm(d1[k2], d0[k2], 0x05040100u);
        *reinterpret_cast<unsigned int*>(&Vt[0][(vd + 2 * k2 + 1) * VST + vkv]) =
            __builtin_amdgcn_perm(d1[k2], d0[k2], 0x07060302u);
      }
    }
    __syncthreads();

    f32x4 oacc[2][4];
    float l_part[2];
#pragma unroll
    for (int mq = 0; mq < 2; ++mq) {
#pragma unroll
      for (int nd = 0; nd < 4; ++nd) oacc[mq][nd] = f32x4{0.f, 0.f, 0.f, 0.f};
      l_part[mq] = 0.f;
    }

    uint4 va0, va1;
    for (int t = 0; t < nT; ++t) {
      const int cur = t & 1;
      const int tn = (t + 1 < nT) ? (t + 1) : t;
      const size_t kv0n = (size_t)tn * 64;

      // prefetch next K frags + V tile (in flight during compute)
#pragma unroll
      for (int kk = 0; kk < 2; ++kk)
#pragma unroll
        for (int nk = 0; nk < 4; ++nk)
          kn[kk][nk] = *reinterpret_cast<const bf16x8*>(
              Kh + (kv0n + nk * 16 + r) * DH2 + kk * 32 + g * 8);
      va0 = *reinterpret_cast<const uint4*>(Vh + (kv0n + vkv) * DH2 + vd);
      va1 = *reinterpret_cast<const uint4*>(Vh + (kv0n + vkv + 1) * DH2 + vd);

      if (t < myT) {
        const int kv0 = t * 64;
        // S^T = K @ Q^T : lane holds S[kv=nk*16+g*4+j][q=mq*16+r]
        f32x4 sacc[2][4];
#pragma unroll
        for (int mq = 0; mq < 2; ++mq)
#pragma unroll
          for (int nk = 0; nk < 4; ++nk) sacc[mq][nk] = f32x4{0.f, 0.f, 0.f, 0.f};
        __builtin_amdgcn_s_setprio(1);
#pragma unroll
        for (int kk = 0; kk < 2; ++kk)
#pragma unroll
          for (int mq = 0; mq < 2; ++mq)
#pragma unroll
            for (int nk = 0; nk < 4; ++nk)
              sacc[mq][nk] = mfma16(kc[kk][nk], qf[mq][kk], sacc[mq][nk]);
        __builtin_amdgcn_s_setprio(0);

        if (t == myT - 1) {   // causal mask on diagonal tile (raw scores)
#pragma unroll
          for (int mq = 0; mq < 2; ++mq) {
            const int qg = q0w + mq * 16 + r;
#pragma unroll
            for (int nk = 0; nk < 4; ++nk)
#pragma unroll
              for (int j = 0; j < 4; ++j) {
                int kg = kv0 + nk * 16 + g * 4 + j;
                if (kg > qg) sacc[mq][nk][j] = NEG_INF;
              }
          }
        }

        // p = exp2(s*C - M0)  (fixed shift: exact softmax, no running max)
        bf16x4 pa[2][4];
#pragma unroll
        for (int mq = 0; mq < 2; ++mq) {
          float ls = 0.f;
#pragma unroll
          for (int nk = 0; nk < 4; ++nk) {
            float p0 = __builtin_amdgcn_exp2f(fmaf(sacc[mq][nk][0], C, -M0));
            float p1 = __builtin_amdgcn_exp2f(fmaf(sacc[mq][nk][1], C, -M0));
            float p2 = __builtin_amdgcn_exp2f(fmaf(sacc[mq][nk][2], C, -M0));
            float p3 = __builtin_amdgcn_exp2f(fmaf(sacc[mq][nk][3], C, -M0));
            ls += (p0 + p1) + (p2 + p3);
            pa[mq][nk] = bf16x4{(short)f2bf(p0), (short)f2bf(p1),
                                (short)f2bf(p2), (short)f2bf(p3)};
          }
          l_part[mq] += ls;
        }

        // PV: O += P @ V via 16x16x16; B-frag = V^T[d=nd*16+r][kv=nk*16+4g+j]
        __builtin_amdgcn_s_setprio(1);
#pragma unroll
        for (int nd = 0; nd < 4; ++nd) {
          bf16x4 vb[4];
#pragma unroll
          for (int nk = 0; nk < 4; ++nk)
            vb[nk] = *reinterpret_cast<const bf16x4*>(
                &Vt[cur][(nd * 16 + r) * VST + nk * 16 + 4 * g]);
#pragma unroll
          for (int mq = 0; mq < 2; ++mq)
#pragma unroll
            for (int nk = 0; nk < 4; ++nk)
              oacc[mq][nd] = mfma16k16(pa[mq][nk], vb[nk], oacc[mq][nd]);
        }
        __builtin_amdgcn_s_setprio(0);
      }

      // stage next V tile (waits on va prefetch)
      {
        const unsigned int* d0 = reinterpret_cast<const unsigned int*>(&va0);
        const unsigned int* d1 = reinterpret_cast<const unsigned int*>(&va1);
#pragma unroll
        for (int k2 = 0; k2 < 4; ++k2) {
          *reinterpret_cast<unsigned int*>(&Vt[cur ^ 1][(vd + 2 * k2) * VST + vkv]) =
              __builtin_amdgcn_perm(d1[k2], d0[k2], 0x05040100u);
          *reinterpret_cast<unsigned int*>(&Vt[cur ^ 1][(vd + 2 * k2 + 1) * VST + vkv]) =
              __builtin_amdgcn_perm(d1[k2], d0[k2], 0x07060302u);
        }
      }
#pragma unroll
      for (int kk = 0; kk < 2; ++kk)
#pragma unroll
        for (int nk = 0; nk < 4; ++nk) kc[kk][nk] = kn[kk][nk];
      __syncthreads();
    }

    // epilogue: O rows q=mq*16+4g+j, cols d=nd*16+r
#pragma unroll
    for (int mq = 0; mq < 2; ++mq) {
      float l = l_part[mq];
      l += __shfl_xor(l, 16);
      l += __shfl_xor(l, 32);
#pragma unroll
      for (int j = 0; j < 4; ++j) {
        float inv = 1.0f / __shfl(l, g * 4 + j);
        int srow = q0w + mq * 16 + g * 4 + j;
#pragma unroll
        for (int nd = 0; nd < 4; ++nd) {
          int d = nd * 16 + r;
          AO[(size_t)(bb * SEQ + srow) * DM + h * DH2 + d] = f2bf(oacc[mq][nd][j] * inv);
        }
      }
    }
  }
}

extern "C" void kernel_launch(void* const* d_in, const int* in_sizes, int n_in,
                              void* d_out, int out_size, void* d_ws, size_t ws_size,
                              hipStream_t stream) {
  const float* x  = (const float*)d_in[0];
  const float* WQ = (const float*)d_in[1];
  const float* WK = (const float*)d_in[2];
  const float* WV = (const float*)d_in[3];
  const float* WO = (const float*)d_in[4];
  const int* pos  = (const int*)d_in[5];

  char* ws = (char*)d_ws;
  unsigned short* xb  = (unsigned short*)(ws + 0);
  unsigned short* wqb = (unsigned short*)(ws + (16u << 20));  // wq|wk|wv contiguous
  unsigned short* wkb = (unsigned short*)(ws + (18u << 20));
  unsigned short* wvb = (unsigned short*)(ws + (20u << 20));
  unsigned short* wob = (unsigned short*)(ws + (22u << 20));
  unsigned short* Qb  = (unsigned short*)(ws + (24u << 20));
  unsigned short* Kb  = (unsigned short*)(ws + (40u << 20));
  unsigned short* Vb  = (unsigned short*)(ws + (56u << 20));
  unsigned short* AO  = (unsigned short*)(ws + (72u << 20));
  float2* tab = (float2*)(ws + (88u << 20));

  cast_kernel<<<2048, 256, 0, stream>>>(x, xb, NROWS * DM / 4);
  cast_kernel<<<256, 256, 0, stream>>>(WQ, wqb, DM * DM / 4);
  cast_kernel<<<256, 256, 0, stream>>>(WK, wkb, DM * DM / 4);
  cast_kernel<<<256, 256, 0, stream>>>(WV, wvb, DM * DM / 4);
  cast_kernel<<<256, 256, 0, stream>>>(WO, wob, DM * DM / 4);
  rope_table_kernel<<<(SEQ * 32 + 255) / 256, 256, 0, stream>>>(tab, pos);

  gemm_qkv<<<dim3(NROWS / 128, 24), 256, 0, stream>>>(xb, wqb, Qb, Kb, Vb, tab);
  flash_attn<<<dim3(8, NB * NH), 256, 0, stream>>>(Qb, Kb, Vb, AO);
  gemm_bt0<<<dim3(NROWS / 128, DM / 128), 256, 0, stream>>>(AO, wob, (float*)d_out);
}

// Round 7
// 204.209 us; speedup vs baseline: 1.3030x; 1.1325x over previous
//
#include <hip/hip_runtime.h>
#include <hip/hip_bf16.h>
#include <math.h>

constexpr int NB   = 4;
constexpr int SEQ  = 2048;
constexpr int DM   = 1024;
constexpr int NH   = 16;
constexpr int DH2  = 64;
constexpr int NROWS = NB * SEQ; // 8192

typedef __attribute__((ext_vector_type(8))) short bf16x8;
typedef __attribute__((ext_vector_type(4))) short bf16x4;
typedef __attribute__((ext_vector_type(4))) float f32x4;

__device__ __forceinline__ unsigned short f2bf(float f) {
  __hip_bfloat16 h = __float2bfloat16(f);
  return *reinterpret_cast<unsigned short*>(&h);
}

__device__ __forceinline__ f32x4 mfma16(bf16x8 a, bf16x8 b, f32x4 c) {
  return __builtin_amdgcn_mfma_f32_16x16x32_bf16(a, b, c, 0, 0, 0);
}

// 16x16x16 bf16 MFMA via inline asm (A/B = 4 bf16 = 2 VGPR)
__device__ __forceinline__ f32x4 mfma16k16(bf16x4 a, bf16x4 b, f32x4 c) {
  asm("v_mfma_f32_16x16x16_bf16 %0, %1, %2, %0" : "+v"(c) : "v"(a), "v"(b));
  return c;
}

__device__ __forceinline__ void gload_lds16(const void* g, void* l) {
  __builtin_amdgcn_global_load_lds(
      (const __attribute__((address_space(1))) void*)g,
      (__attribute__((address_space(3))) void*)l, 16, 0, 0);
}

// ---------------- cast f32 -> bf16 (x) ----------------
__global__ void cast_kernel(const float* __restrict__ in,
                            unsigned short* __restrict__ out, int n4) {
  int i = blockIdx.x * blockDim.x + threadIdx.x;
  int stride = gridDim.x * blockDim.x;
  for (int idx = i; idx < n4; idx += stride) {
    float4 v = reinterpret_cast<const float4*>(in)[idx];
    ushort4 o;
    o.x = f2bf(v.x); o.y = f2bf(v.y); o.z = f2bf(v.z); o.w = f2bf(v.w);
    reinterpret_cast<ushort4*>(out)[idx] = o;
  }
}

// ---------------- fused 4-weight cast: WQ,WK,WV,WO -> contiguous bf16 ----------
__global__ void cast4_kernel(const float* __restrict__ w0, const float* __restrict__ w1,
                             const float* __restrict__ w2, const float* __restrict__ w3,
                             unsigned short* __restrict__ out) {
  constexpr int N4 = DM * DM / 4;  // float4 count per weight
  int idx = blockIdx.x * blockDim.x + threadIdx.x;
  if (idx >= N4) return;
  const float* ins[4] = {w0, w1, w2, w3};
#pragma unroll
  for (int wi = 0; wi < 4; ++wi) {
    float4 v = reinterpret_cast<const float4*>(ins[wi])[idx];
    ushort4 o;
    o.x = f2bf(v.x); o.y = f2bf(v.y); o.z = f2bf(v.z); o.w = f2bf(v.w);
    reinterpret_cast<ushort4*>(out + (size_t)wi * DM * DM)[idx] = o;
  }
}

// ---------------- rope table ----------------
__global__ void rope_table_kernel(float2* __restrict__ tab, const int* __restrict__ pos) {
  int idx = blockIdx.x * blockDim.x + threadIdx.x;
  if (idx >= SEQ * 32) return;
  int s = idx >> 5, i = idx & 31;
  float inv = powf(10000.0f, -(float)i * (1.0f / 32.0f));
  float ang = (float)pos[s] * inv;
  tab[idx] = make_float2(cosf(ang), sinf(ang));
}

// ---------------- GEMM: C = A @ B^T (R2-R5 proven structure) ----------------
// MODE 0: f32 out [M][DM]; MODE 1: bf16 out to [B,H,S,dh] with RoPE; MODE 2: same, no RoPE.
template<int MODE>
__global__ __launch_bounds__(256)
void gemm_bt(const unsigned short* __restrict__ Ag,
             const unsigned short* __restrict__ Bg,
             void* __restrict__ Cout,
             const float2* __restrict__ tab)
{
  constexpr int K = DM;
  __shared__ unsigned short As[128 * 32];
  __shared__ unsigned short Bs[128 * 32];
  const int tid = threadIdx.x;
  const int w = tid >> 6, lane = tid & 63;
  const int wr = w >> 1, wc = w & 1;
  const int r = lane & 15, g = lane >> 4;
  const int rowTile = blockIdx.x, colTile = blockIdx.y;
  const unsigned short* Abase = Ag + (size_t)rowTile * 128 * K;
  const unsigned short* Bbase = Bg + (size_t)colTile * 128 * K;

  f32x4 acc[4][4];
#pragma unroll
  for (int m = 0; m < 4; ++m)
#pragma unroll
    for (int n = 0; n < 4; ++n) acc[m][n] = f32x4{0.f, 0.f, 0.f, 0.f};

  const int e0 = w * 1024 + lane * 8;

  for (int k0 = 0; k0 < K; k0 += 32) {
#pragma unroll
    for (int c = 0; c < 2; ++c) {
      int e = e0 + c * 512;
      int trow = e >> 5, tcol = e & 31;
      gload_lds16(Abase + (size_t)trow * K + k0 + tcol, As + (w * 2 + c) * 512);
      gload_lds16(Bbase + (size_t)trow * K + k0 + tcol, Bs + (w * 2 + c) * 512);
    }
    __syncthreads();
    bf16x8 a[4], b[4];
#pragma unroll
    for (int m = 0; m < 4; ++m)
      a[m] = *reinterpret_cast<const bf16x8*>(As + (wr * 64 + m * 16 + r) * 32 + g * 8);
#pragma unroll
    for (int n = 0; n < 4; ++n)
      b[n] = *reinterpret_cast<const bf16x8*>(Bs + (wc * 64 + n * 16 + r) * 32 + g * 8);
#pragma unroll
    for (int m = 0; m < 4; ++m)
#pragma unroll
      for (int n = 0; n < 4; ++n)
        acc[m][n] = mfma16(a[m], b[n], acc[m][n]);
    __syncthreads();
  }

  const int row0 = rowTile * 128 + wr * 64;
  const int col0 = colTile * 128 + wc * 64;
  if constexpr (MODE == 0) {
    float* C = reinterpret_cast<float*>(Cout);
#pragma unroll
    for (int m = 0; m < 4; ++m)
#pragma unroll
      for (int n = 0; n < 4; ++n)
#pragma unroll
        for (int j = 0; j < 4; ++j) {
          int rr = row0 + m * 16 + g * 4 + j;
          int cc = col0 + n * 16 + r;
          C[(size_t)rr * DM + cc] = acc[m][n][j];
        }
  } else {
    unsigned short* Ob = reinterpret_cast<unsigned short*>(Cout);
#pragma unroll
    for (int m = 0; m < 4; ++m)
#pragma unroll
      for (int n = 0; n < 4; ++n)
#pragma unroll
        for (int j = 0; j < 4; ++j) {
          int rr = row0 + m * 16 + g * 4 + j;
          int ee = col0 + n * 16 + r;
          float val = acc[m][n][j];
          if constexpr (MODE == 1) {
            float partner = __shfl_xor(val, 1);
            int dd = ee & 63;
            int sr = rr & (SEQ - 1);
            float2 cs = tab[sr * 32 + (dd >> 1)];
            val = val * cs.x + (((ee & 1) == 0) ? -partner : partner) * cs.y;
          }
          int bb = rr >> 11;
          int sr2 = rr & (SEQ - 1);
          int h = ee >> 6, d = ee & 63;
          Ob[((size_t)(bb * NH + h) * SEQ + sr2) * DH2 + d] = f2bf(val);
        }
  }
}

// ---------------- flash attention v6: R3 structure + fixed-max softmax ----------
__global__ __launch_bounds__(256)
void flash_attn(const unsigned short* __restrict__ Qb,
                const unsigned short* __restrict__ Kb,
                const unsigned short* __restrict__ Vb,
                unsigned short* __restrict__ AO)
{
  constexpr int VST = 68;  // V^T lds row stride (shorts)
  __shared__ unsigned short Vt[2][64 * VST];
  const int tid = threadIdx.x;
  const int w = tid >> 6, lane = tid & 63;
  const int r = lane & 15, g = lane >> 4;
  const int pr = blockIdx.x;        // pair index 0..7
  const int bh = blockIdx.y;
  const unsigned short* Qh = Qb + (size_t)bh * SEQ * DH2;
  const unsigned short* Kh = Kb + (size_t)bh * SEQ * DH2;
  const unsigned short* Vh = Vb + (size_t)bh * SEQ * DH2;
  const int bb = bh >> 4, h = bh & 15;
  const int vd  = (lane & 7) * 8;
  const int vkv = w * 16 + (lane >> 3) * 2;
  const float C = 0.18033688f;        // 0.125 * log2(e)
  const float M0 = 11.5415603f;       // 8 * log2(e): fixed shift (exact softmax, shifted)
  const float NEG_INF = -__builtin_inff();

  for (int ctx = 0; ctx < 2; ++ctx) {
    const int qt = ctx ? pr : (15 - pr);   // big tile first; pair sums to 34 tiles
    const int q0w = qt * 128 + w * 32;
    const int nT  = 2 * qt + 2;
    const int myT = 2 * qt + 1 + (w >> 1);

    // Q fragments (B-operand of swapped QK): col=q0w+mq*16+r, k=kk*32+g*8
    bf16x8 qf[2][2];
#pragma unroll
    for (int mq = 0; mq < 2; ++mq)
#pragma unroll
      for (int kk = 0; kk < 2; ++kk)
        qf[mq][kk] = *reinterpret_cast<const bf16x8*>(
            Qh + (size_t)(q0w + mq * 16 + r) * DH2 + kk * 32 + g * 8);

    // K fragments (A-operand): row=kv0+nk*16+r, k=kk*32+g*8
    bf16x8 kc[2][4], kn[2][4];
#pragma unroll
    for (int kk = 0; kk < 2; ++kk)
#pragma unroll
      for (int nk = 0; nk < 4; ++nk)
        kc[kk][nk] = *reinterpret_cast<const bf16x8*>(
            Kh + (size_t)(nk * 16 + r) * DH2 + kk * 32 + g * 8);

    // stage V tile 0 as V^T (perm pack)
    {
      uint4 a0 = *reinterpret_cast<const uint4*>(Vh + (size_t)vkv * DH2 + vd);
      uint4 a1 = *reinterpret_cast<const uint4*>(Vh + (size_t)(vkv + 1) * DH2 + vd);
      const unsigned int* d0 = reinterpret_cast<const unsigned int*>(&a0);
      const unsigned int* d1 = reinterpret_cast<const unsigned int*>(&a1);
#pragma unroll
      for (int k2 = 0; k2 < 4; ++k2) {
        *reinterpret_cast<unsigned int*>(&Vt[0][(vd + 2 * k2) * VST + vkv]) =
            __builtin_amdgcn_perm(d1[k2], d0[k2], 0x05040100u);
        *reinterpret_cast<unsigned int*>(&Vt[0][(vd + 2 * k2 + 1) * VST + vkv]) =
            __builtin_amdgcn_perm(d1[k2], d0[k2], 0x07060302u);
      }
    }
    __syncthreads();

    f32x4 oacc[2][4];
    float l_part[2];
#pragma unroll
    for (int mq = 0; mq < 2; ++mq) {
#pragma unroll
      for (int nd = 0; nd < 4; ++nd) oacc[mq][nd] = f32x4{0.f, 0.f, 0.f, 0.f};
      l_part[mq] = 0.f;
    }

    uint4 va0, va1;
    for (int t = 0; t < nT; ++t) {
      const int cur = t & 1;
      const int tn = (t + 1 < nT) ? (t + 1) : t;
      const size_t kv0n = (size_t)tn * 64;

      // prefetch next K frags + V tile (in flight during compute)
#pragma unroll
      for (int kk = 0; kk < 2; ++kk)
#pragma unroll
        for (int nk = 0; nk < 4; ++nk)
          kn[kk][nk] = *reinterpret_cast<const bf16x8*>(
              Kh + (kv0n + nk * 16 + r) * DH2 + kk * 32 + g * 8);
      va0 = *reinterpret_cast<const uint4*>(Vh + (kv0n + vkv) * DH2 + vd);
      va1 = *reinterpret_cast<const uint4*>(Vh + (kv0n + vkv + 1) * DH2 + vd);

      if (t < myT) {
        const int kv0 = t * 64;
        // S^T = K @ Q^T : lane holds S[kv=nk*16+g*4+j][q=mq*16+r]
        f32x4 sacc[2][4];
#pragma unroll
        for (int mq = 0; mq < 2; ++mq)
#pragma unroll
          for (int nk = 0; nk < 4; ++nk) sacc[mq][nk] = f32x4{0.f, 0.f, 0.f, 0.f};
        __builtin_amdgcn_s_setprio(1);
#pragma unroll
        for (int kk = 0; kk < 2; ++kk)
#pragma unroll
          for (int mq = 0; mq < 2; ++mq)
#pragma unroll
            for (int nk = 0; nk < 4; ++nk)
              sacc[mq][nk] = mfma16(kc[kk][nk], qf[mq][kk], sacc[mq][nk]);
        __builtin_amdgcn_s_setprio(0);

        if (t == myT - 1) {   // causal mask on diagonal tile (raw scores)
#pragma unroll
          for (int mq = 0; mq < 2; ++mq) {
            const int qg = q0w + mq * 16 + r;
#pragma unroll
            for (int nk = 0; nk < 4; ++nk)
#pragma unroll
              for (int j = 0; j < 4; ++j) {
                int kg = kv0 + nk * 16 + g * 4 + j;
                if (kg > qg) sacc[mq][nk][j] = NEG_INF;
              }
          }
        }

        // p = exp2(s*C - M0)  (fixed shift: exact softmax, no running max)
        bf16x4 pa[2][4];
#pragma unroll
        for (int mq = 0; mq < 2; ++mq) {
          float ls = 0.f;
#pragma unroll
          for (int nk = 0; nk < 4; ++nk) {
            float p0 = __builtin_amdgcn_exp2f(fmaf(sacc[mq][nk][0], C, -M0));
            float p1 = __builtin_amdgcn_exp2f(fmaf(sacc[mq][nk][1], C, -M0));
            float p2 = __builtin_amdgcn_exp2f(fmaf(sacc[mq][nk][2], C, -M0));
            float p3 = __builtin_amdgcn_exp2f(fmaf(sacc[mq][nk][3], C, -M0));
            ls += (p0 + p1) + (p2 + p3);
            pa[mq][nk] = bf16x4{(short)f2bf(p0), (short)f2bf(p1),
                                (short)f2bf(p2), (short)f2bf(p3)};
          }
          l_part[mq] += ls;
        }

        // PV: O += P @ V via 16x16x16; B-frag = V^T[d=nd*16+r][kv=nk*16+4g+j]
        __builtin_amdgcn_s_setprio(1);
#pragma unroll
        for (int nd = 0; nd < 4; ++nd) {
          bf16x4 vb[4];
#pragma unroll
          for (int nk = 0; nk < 4; ++nk)
            vb[nk] = *reinterpret_cast<const bf16x4*>(
                &Vt[cur][(nd * 16 + r) * VST + nk * 16 + 4 * g]);
#pragma unroll
          for (int mq = 0; mq < 2; ++mq)
#pragma unroll
            for (int nk = 0; nk < 4; ++nk)
              oacc[mq][nd] = mfma16k16(pa[mq][nk], vb[nk], oacc[mq][nd]);
        }
        __builtin_amdgcn_s_setprio(0);
      }

      // stage next V tile (waits on va prefetch)
      {
        const unsigned int* d0 = reinterpret_cast<const unsigned int*>(&va0);
        const unsigned int* d1 = reinterpret_cast<const unsigned int*>(&va1);
#pragma unroll
        for (int k2 = 0; k2 < 4; ++k2) {
          *reinterpret_cast<unsigned int*>(&Vt[cur ^ 1][(vd + 2 * k2) * VST + vkv]) =
              __builtin_amdgcn_perm(d1[k2], d0[k2], 0x05040100u);
          *reinterpret_cast<unsigned int*>(&Vt[cur ^ 1][(vd + 2 * k2 + 1) * VST + vkv]) =
              __builtin_amdgcn_perm(d1[k2], d0[k2], 0x07060302u);
        }
      }
#pragma unroll
      for (int kk = 0; kk < 2; ++kk)
#pragma unroll
        for (int nk = 0; nk < 4; ++nk) kc[kk][nk] = kn[kk][nk];
      __syncthreads();
    }

    // epilogue: O rows q=mq*16+4g+j, cols d=nd*16+r
#pragma unroll
    for (int mq = 0; mq < 2; ++mq) {
      float l = l_part[mq];
      l += __shfl_xor(l, 16);
      l += __shfl_xor(l, 32);
#pragma unroll
      for (int j = 0; j < 4; ++j) {
        float inv = 1.0f / __shfl(l, g * 4 + j);
        int srow = q0w + mq * 16 + g * 4 + j;
#pragma unroll
        for (int nd = 0; nd < 4; ++nd) {
          int d = nd * 16 + r;
          AO[(size_t)(bb * SEQ + srow) * DM + h * DH2 + d] = f2bf(oacc[mq][nd][j] * inv);
        }
      }
    }
  }
}

extern "C" void kernel_launch(void* const* d_in, const int* in_sizes, int n_in,
                              void* d_out, int out_size, void* d_ws, size_t ws_size,
                              hipStream_t stream) {
  const float* x  = (const float*)d_in[0];
  const float* WQ = (const float*)d_in[1];
  const float* WK = (const float*)d_in[2];
  const float* WV = (const float*)d_in[3];
  const float* WO = (const float*)d_in[4];
  const int* pos  = (const int*)d_in[5];

  char* ws = (char*)d_ws;
  unsigned short* xb  = (unsigned short*)(ws + 0);
  unsigned short* wqb = (unsigned short*)(ws + (16u << 20));  // wq|wk|wv|wo contiguous
  unsigned short* wkb = (unsigned short*)(ws + (18u << 20));
  unsigned short* wvb = (unsigned short*)(ws + (20u << 20));
  unsigned short* wob = (unsigned short*)(ws + (22u << 20));
  unsigned short* Qb  = (unsigned short*)(ws + (24u << 20));
  unsigned short* Kb  = (unsigned short*)(ws + (40u << 20));
  unsigned short* Vb  = (unsigned short*)(ws + (56u << 20));
  unsigned short* AO  = (unsigned short*)(ws + (72u << 20));
  float2* tab = (float2*)(ws + (88u << 20));

  cast_kernel<<<2048, 256, 0, stream>>>(x, xb, NROWS * DM / 4);
  cast4_kernel<<<DM * DM / 4 / 256, 256, 0, stream>>>(WQ, WK, WV, WO, wqb);
  rope_table_kernel<<<(SEQ * 32 + 255) / 256, 256, 0, stream>>>(tab, pos);

  dim3 gproj(NROWS / 128, DM / 128);
  gemm_bt<1><<<gproj, 256, 0, stream>>>(xb, wqb, (void*)Qb, tab);
  gemm_bt<1><<<gproj, 256, 0, stream>>>(xb, wkb, (void*)Kb, tab);
  gemm_bt<2><<<gproj, 256, 0, stream>>>(xb, wvb, (void*)Vb, nullptr);
  flash_attn<<<dim3(8, NB * NH), 256, 0, stream>>>(Qb, Kb, Vb, AO);
  gemm_bt<0><<<gproj, 256, 0, stream>>>(AO, wob, d_out, nullptr);
}

// Round 8
// 195.440 us; speedup vs baseline: 1.3615x; 1.0449x over previous
//
#include <hip/hip_runtime.h>
#include <hip/hip_bf16.h>
#include <math.h>

constexpr int NB   = 4;
constexpr int SEQ  = 2048;
constexpr int DM   = 1024;
constexpr int NH   = 16;
constexpr int DH2  = 64;
constexpr int NROWS = NB * SEQ; // 8192

typedef __attribute__((ext_vector_type(8))) short bf16x8;
typedef __attribute__((ext_vector_type(4))) short bf16x4;
typedef __attribute__((ext_vector_type(4))) float f32x4;

__device__ __forceinline__ unsigned short f2bf(float f) {
  __hip_bfloat16 h = __float2bfloat16(f);
  return *reinterpret_cast<unsigned short*>(&h);
}

__device__ __forceinline__ f32x4 mfma16(bf16x8 a, bf16x8 b, f32x4 c) {
  return __builtin_amdgcn_mfma_f32_16x16x32_bf16(a, b, c, 0, 0, 0);
}

// 16x16x16 bf16 MFMA via inline asm (A/B = 4 bf16 = 2 VGPR)
__device__ __forceinline__ f32x4 mfma16k16(bf16x4 a, bf16x4 b, f32x4 c) {
  asm("v_mfma_f32_16x16x16_bf16 %0, %1, %2, %0" : "+v"(c) : "v"(a), "v"(b));
  return c;
}

__device__ __forceinline__ void gload_lds16(const void* g, void* l) {
  __builtin_amdgcn_global_load_lds(
      (const __attribute__((address_space(1))) void*)g,
      (__attribute__((address_space(3))) void*)l, 16, 0, 0);
}

// ---------------- cast f32 -> bf16 (x) ----------------
__global__ void cast_kernel(const float* __restrict__ in,
                            unsigned short* __restrict__ out, int n4) {
  int i = blockIdx.x * blockDim.x + threadIdx.x;
  int stride = gridDim.x * blockDim.x;
  for (int idx = i; idx < n4; idx += stride) {
    float4 v = reinterpret_cast<const float4*>(in)[idx];
    ushort4 o;
    o.x = f2bf(v.x); o.y = f2bf(v.y); o.z = f2bf(v.z); o.w = f2bf(v.w);
    reinterpret_cast<ushort4*>(out)[idx] = o;
  }
}

// ---------------- fused 4-weight cast ----------------
__global__ void cast4_kernel(const float* __restrict__ w0, const float* __restrict__ w1,
                             const float* __restrict__ w2, const float* __restrict__ w3,
                             unsigned short* __restrict__ out) {
  constexpr int N4 = DM * DM / 4;
  int idx = blockIdx.x * blockDim.x + threadIdx.x;
  if (idx >= N4) return;
  const float* ins[4] = {w0, w1, w2, w3};
#pragma unroll
  for (int wi = 0; wi < 4; ++wi) {
    float4 v = reinterpret_cast<const float4*>(ins[wi])[idx];
    ushort4 o;
    o.x = f2bf(v.x); o.y = f2bf(v.y); o.z = f2bf(v.z); o.w = f2bf(v.w);
    reinterpret_cast<ushort4*>(out + (size_t)wi * DM * DM)[idx] = o;
  }
}

// ---------------- rope table ----------------
__global__ void rope_table_kernel(float2* __restrict__ tab, const int* __restrict__ pos) {
  int idx = blockIdx.x * blockDim.x + threadIdx.x;
  if (idx >= SEQ * 32) return;
  int s = idx >> 5, i = idx & 31;
  float inv = powf(10000.0f, -(float)i * (1.0f / 32.0f));
  float ang = (float)pos[s] * inv;
  tab[idx] = make_float2(cosf(ang), sinf(ang));
}

// ---------------- GEMM: C = A @ B^T (proven m97-class structure) ----------------
template<int MODE>
__global__ __launch_bounds__(256)
void gemm_bt(const unsigned short* __restrict__ Ag,
             const unsigned short* __restrict__ Bg,
             void* __restrict__ Cout,
             const float2* __restrict__ tab)
{
  constexpr int K = DM;
  __shared__ unsigned short As[128 * 32];
  __shared__ unsigned short Bs[128 * 32];
  const int tid = threadIdx.x;
  const int w = tid >> 6, lane = tid & 63;
  const int wr = w >> 1, wc = w & 1;
  const int r = lane & 15, g = lane >> 4;
  const int rowTile = blockIdx.x, colTile = blockIdx.y;
  const unsigned short* Abase = Ag + (size_t)rowTile * 128 * K;
  const unsigned short* Bbase = Bg + (size_t)colTile * 128 * K;

  f32x4 acc[4][4];
#pragma unroll
  for (int m = 0; m < 4; ++m)
#pragma unroll
    for (int n = 0; n < 4; ++n) acc[m][n] = f32x4{0.f, 0.f, 0.f, 0.f};

  const int e0 = w * 1024 + lane * 8;

  for (int k0 = 0; k0 < K; k0 += 32) {
#pragma unroll
    for (int c = 0; c < 2; ++c) {
      int e = e0 + c * 512;
      int trow = e >> 5, tcol = e & 31;
      gload_lds16(Abase + (size_t)trow * K + k0 + tcol, As + (w * 2 + c) * 512);
      gload_lds16(Bbase + (size_t)trow * K + k0 + tcol, Bs + (w * 2 + c) * 512);
    }
    __syncthreads();
    bf16x8 a[4], b[4];
#pragma unroll
    for (int m = 0; m < 4; ++m)
      a[m] = *reinterpret_cast<const bf16x8*>(As + (wr * 64 + m * 16 + r) * 32 + g * 8);
#pragma unroll
    for (int n = 0; n < 4; ++n)
      b[n] = *reinterpret_cast<const bf16x8*>(Bs + (wc * 64 + n * 16 + r) * 32 + g * 8);
#pragma unroll
    for (int m = 0; m < 4; ++m)
#pragma unroll
      for (int n = 0; n < 4; ++n)
        acc[m][n] = mfma16(a[m], b[n], acc[m][n]);
    __syncthreads();
  }

  const int row0 = rowTile * 128 + wr * 64;
  const int col0 = colTile * 128 + wc * 64;
  if constexpr (MODE == 0) {
    float* C = reinterpret_cast<float*>(Cout);
#pragma unroll
    for (int m = 0; m < 4; ++m)
#pragma unroll
      for (int n = 0; n < 4; ++n)
#pragma unroll
        for (int j = 0; j < 4; ++j) {
          int rr = row0 + m * 16 + g * 4 + j;
          int cc = col0 + n * 16 + r;
          C[(size_t)rr * DM + cc] = acc[m][n][j];
        }
  } else {
    unsigned short* Ob = reinterpret_cast<unsigned short*>(Cout);
#pragma unroll
    for (int m = 0; m < 4; ++m)
#pragma unroll
      for (int n = 0; n < 4; ++n)
#pragma unroll
        for (int j = 0; j < 4; ++j) {
          int rr = row0 + m * 16 + g * 4 + j;
          int ee = col0 + n * 16 + r;
          float val = acc[m][n][j];
          if constexpr (MODE == 1) {
            float partner = __shfl_xor(val, 1);
            int dd = ee & 63;
            int sr = rr & (SEQ - 1);
            float2 cs = tab[sr * 32 + (dd >> 1)];
            val = val * cs.x + (((ee & 1) == 0) ? -partner : partner) * cs.y;
          }
          int bb = rr >> 11;
          int sr2 = rr & (SEQ - 1);
          int h = ee >> 6, d = ee & 63;
          Ob[((size_t)(bb * NH + h) * SEQ + sr2) * DH2 + d] = f2bf(val);
        }
  }
}

// ---------------- flash attention v7: K via swizzled global_load_lds ----------
// K LDS layout: linear [row][col16^(row&7)] (16B chunks); source pre-swizzled so
// gload_lds16 (linear dest) + swizzled ds_read = correct (both-sides rule).
__global__ __launch_bounds__(256)
void flash_attn(const unsigned short* __restrict__ Qb,
                const unsigned short* __restrict__ Kb,
                const unsigned short* __restrict__ Vb,
                unsigned short* __restrict__ AO)
{
  constexpr int VST = 68;  // V^T lds row stride (shorts)
  __shared__ unsigned short Kl[2 * 64 * 64];   // 16 KB double-buffered K tile
  __shared__ unsigned short Vt[2][64 * VST];
  const int tid = threadIdx.x;
  const int w = tid >> 6, lane = tid & 63;
  const int r = lane & 15, g = lane >> 4;
  const int pr = blockIdx.x;        // pair index 0..7
  const int bh = blockIdx.y;
  const unsigned short* Qh = Qb + (size_t)bh * SEQ * DH2;
  const unsigned short* Kh = Kb + (size_t)bh * SEQ * DH2;
  const unsigned short* Vh = Vb + (size_t)bh * SEQ * DH2;
  const int bb = bh >> 4, h = bh & 15;
  const int vd  = (lane & 7) * 8;
  const int vkv = w * 16 + (lane >> 3) * 2;
  const float C = 0.18033688f;        // 0.125 * log2(e)
  const float M0 = 11.5415603f;       // 8 * log2(e): fixed shift (exact softmax, shifted)
  const float NEG_INF = -__builtin_inff();

  // K staging: round 0 rows 0..31 (shorts 0..2047), round 1 rows 32..63 (+2048)
  const int krow   = tid >> 3;                       // 0..31
  const int kcol16 = (tid & 7) ^ (krow & 7);         // swizzled source chunk
  const int kgoff  = krow * 64 + kcol16 * 8;         // shorts, round-0 source offset
  // K read bases (shorts within one buf): kk=0 and kk=1 (col16 differs by ^4)
  const int kread0 = r * 64 + ((g ^ (r & 7)) * 8);
  const int kread1 = r * 64 + (((4 ^ g) ^ (r & 7)) * 8);

  for (int ctx = 0; ctx < 2; ++ctx) {
    const int qt = ctx ? pr : (15 - pr);   // big tile first; pair sums to 34 tiles
    const int q0w = qt * 128 + w * 32;
    const int nT  = 2 * qt + 2;
    const int myT = 2 * qt + 1 + (w >> 1);

    // Q fragments (B-operand of swapped QK): col=q0w+mq*16+r, k=kk*32+g*8
    bf16x8 qf[2][2];
#pragma unroll
    for (int mq = 0; mq < 2; ++mq)
#pragma unroll
      for (int kk = 0; kk < 2; ++kk)
        qf[mq][kk] = *reinterpret_cast<const bf16x8*>(
            Qh + (size_t)(q0w + mq * 16 + r) * DH2 + kk * 32 + g * 8);

    // prologue: stage K tile 0 -> buf0 (async, zero VALU), V tile 0 -> Vt[0]
    gload_lds16(Kh + kgoff, Kl + w * 512);
    gload_lds16(Kh + kgoff + 2048, Kl + 2048 + w * 512);
    {
      uint4 a0 = *reinterpret_cast<const uint4*>(Vh + (size_t)vkv * DH2 + vd);
      uint4 a1 = *reinterpret_cast<const uint4*>(Vh + (size_t)(vkv + 1) * DH2 + vd);
      const unsigned int* d0 = reinterpret_cast<const unsigned int*>(&a0);
      const unsigned int* d1 = reinterpret_cast<const unsigned int*>(&a1);
#pragma unroll
      for (int k2 = 0; k2 < 4; ++k2) {
        *reinterpret_cast<unsigned int*>(&Vt[0][(vd + 2 * k2) * VST + vkv]) =
            __builtin_amdgcn_perm(d1[k2], d0[k2], 0x05040100u);
        *reinterpret_cast<unsigned int*>(&Vt[0][(vd + 2 * k2 + 1) * VST + vkv]) =
            __builtin_amdgcn_perm(d1[k2], d0[k2], 0x07060302u);
      }
    }
    __syncthreads();

    f32x4 oacc[2][4];
    float l_part[2];
#pragma unroll
    for (int mq = 0; mq < 2; ++mq) {
#pragma unroll
      for (int nd = 0; nd < 4; ++nd) oacc[mq][nd] = f32x4{0.f, 0.f, 0.f, 0.f};
      l_part[mq] = 0.f;
    }

    uint4 va0, va1;
    for (int t = 0; t < nT; ++t) {
      const int cur = t & 1;
      const unsigned short* Klp = Kl + (cur ? 4096 : 0);
      unsigned short* Kln = Kl + (cur ? 0 : 4096);
      const bool haveNext = (t + 1 < nT);

      if (haveNext) {
        const size_t kv0n = (size_t)(t + 1) * 64;
        // async K stage into next buf (pre-swizzled source, linear dest)
        gload_lds16(Kh + kv0n * 64 + kgoff, Kln + w * 512);
        gload_lds16(Kh + kv0n * 64 + kgoff + 2048, Kln + 2048 + w * 512);
        // V prefetch to regs
        va0 = *reinterpret_cast<const uint4*>(Vh + (kv0n + vkv) * DH2 + vd);
        va1 = *reinterpret_cast<const uint4*>(Vh + (kv0n + vkv + 1) * DH2 + vd);
      }

      if (t < myT) {
        const int kv0 = t * 64;
        // K fragments from LDS (swizzled read; 2-way max -> b128 floor)
        bf16x8 kf0[4], kf1[4];
#pragma unroll
        for (int nk = 0; nk < 4; ++nk) {
          kf0[nk] = *reinterpret_cast<const bf16x8*>(Klp + kread0 + nk * 1024);
          kf1[nk] = *reinterpret_cast<const bf16x8*>(Klp + kread1 + nk * 1024);
        }
        // S^T = K @ Q^T : lane holds S[kv=nk*16+g*4+j][q=mq*16+r]
        f32x4 sacc[2][4];
#pragma unroll
        for (int mq = 0; mq < 2; ++mq)
#pragma unroll
          for (int nk = 0; nk < 4; ++nk) sacc[mq][nk] = f32x4{0.f, 0.f, 0.f, 0.f};
        __builtin_amdgcn_s_setprio(1);
#pragma unroll
        for (int mq = 0; mq < 2; ++mq)
#pragma unroll
          for (int nk = 0; nk < 4; ++nk)
            sacc[mq][nk] = mfma16(kf0[nk], qf[mq][0], sacc[mq][nk]);
#pragma unroll
        for (int mq = 0; mq < 2; ++mq)
#pragma unroll
          for (int nk = 0; nk < 4; ++nk)
            sacc[mq][nk] = mfma16(kf1[nk], qf[mq][1], sacc[mq][nk]);
        __builtin_amdgcn_s_setprio(0);

        if (t == myT - 1) {   // causal mask on diagonal tile (raw scores)
#pragma unroll
          for (int mq = 0; mq < 2; ++mq) {
            const int qg = q0w + mq * 16 + r;
#pragma unroll
            for (int nk = 0; nk < 4; ++nk)
#pragma unroll
              for (int j = 0; j < 4; ++j) {
                int kg = kv0 + nk * 16 + g * 4 + j;
                if (kg > qg) sacc[mq][nk][j] = NEG_INF;
              }
          }
        }

        // p = exp2(s*C - M0)  (fixed shift: exact softmax, no running max)
        bf16x4 pa[2][4];
#pragma unroll
        for (int mq = 0; mq < 2; ++mq) {
          float ls = 0.f;
#pragma unroll
          for (int nk = 0; nk < 4; ++nk) {
            float p0 = __builtin_amdgcn_exp2f(fmaf(sacc[mq][nk][0], C, -M0));
            float p1 = __builtin_amdgcn_exp2f(fmaf(sacc[mq][nk][1], C, -M0));
            float p2 = __builtin_amdgcn_exp2f(fmaf(sacc[mq][nk][2], C, -M0));
            float p3 = __builtin_amdgcn_exp2f(fmaf(sacc[mq][nk][3], C, -M0));
            ls += (p0 + p1) + (p2 + p3);
            pa[mq][nk] = bf16x4{(short)f2bf(p0), (short)f2bf(p1),
                                (short)f2bf(p2), (short)f2bf(p3)};
          }
          l_part[mq] += ls;
        }

        // PV: O += P @ V via 16x16x16; B-frag = V^T[d=nd*16+r][kv=nk*16+4g+j]
        __builtin_amdgcn_s_setprio(1);
#pragma unroll
        for (int nd = 0; nd < 4; ++nd) {
          bf16x4 vb[4];
#pragma unroll
          for (int nk = 0; nk < 4; ++nk)
            vb[nk] = *reinterpret_cast<const bf16x4*>(
                &Vt[cur][(nd * 16 + r) * VST + nk * 16 + 4 * g]);
#pragma unroll
          for (int mq = 0; mq < 2; ++mq)
#pragma unroll
            for (int nk = 0; nk < 4; ++nk)
              oacc[mq][nd] = mfma16k16(pa[mq][nk], vb[nk], oacc[mq][nd]);
        }
        __builtin_amdgcn_s_setprio(0);
      }

      if (haveNext) {  // stage next V tile (waits on va prefetch)
        const unsigned int* d0 = reinterpret_cast<const unsigned int*>(&va0);
        const unsigned int* d1 = reinterpret_cast<const unsigned int*>(&va1);
#pragma unroll
        for (int k2 = 0; k2 < 4; ++k2) {
          *reinterpret_cast<unsigned int*>(&Vt[cur ^ 1][(vd + 2 * k2) * VST + vkv]) =
              __builtin_amdgcn_perm(d1[k2], d0[k2], 0x05040100u);
          *reinterpret_cast<unsigned int*>(&Vt[cur ^ 1][(vd + 2 * k2 + 1) * VST + vkv]) =
              __builtin_amdgcn_perm(d1[k2], d0[k2], 0x07060302u);
        }
      }
      __syncthreads();
    }

    // epilogue: O rows q=mq*16+4g+j, cols d=nd*16+r
#pragma unroll
    for (int mq = 0; mq < 2; ++mq) {
      float l = l_part[mq];
      l += __shfl_xor(l, 16);
      l += __shfl_xor(l, 32);
#pragma unroll
      for (int j = 0; j < 4; ++j) {
        float inv = 1.0f / __shfl(l, g * 4 + j);
        int srow = q0w + mq * 16 + g * 4 + j;
#pragma unroll
        for (int nd = 0; nd < 4; ++nd) {
          int d = nd * 16 + r;
          AO[(size_t)(bb * SEQ + srow) * DM + h * DH2 + d] = f2bf(oacc[mq][nd][j] * inv);
        }
      }
    }
  }
}

extern "C" void kernel_launch(void* const* d_in, const int* in_sizes, int n_in,
                              void* d_out, int out_size, void* d_ws, size_t ws_size,
                              hipStream_t stream) {
  const float* x  = (const float*)d_in[0];
  const float* WQ = (const float*)d_in[1];
  const float* WK = (const float*)d_in[2];
  const float* WV = (const float*)d_in[3];
  const float* WO = (const float*)d_in[4];
  const int* pos  = (const int*)d_in[5];

  char* ws = (char*)d_ws;
  unsigned short* xb  = (unsigned short*)(ws + 0);
  unsigned short* wqb = (unsigned short*)(ws + (16u << 20));  // wq|wk|wv|wo contiguous
  unsigned short* wkb = (unsigned short*)(ws + (18u << 20));
  unsigned short* wvb = (unsigned short*)(ws + (20u << 20));
  unsigned short* wob = (unsigned short*)(ws + (22u << 20));
  unsigned short* Qb  = (unsigned short*)(ws + (24u << 20));
  unsigned short* Kb  = (unsigned short*)(ws + (40u << 20));
  unsigned short* Vb  = (unsigned short*)(ws + (56u << 20));
  unsigned short* AO  = (unsigned short*)(ws + (72u << 20));
  float2* tab = (float2*)(ws + (88u << 20));

  cast_kernel<<<2048, 256, 0, stream>>>(x, xb, NROWS * DM / 4);
  cast4_kernel<<<DM * DM / 4 / 256, 256, 0, stream>>>(WQ, WK, WV, WO, wqb);
  rope_table_kernel<<<(SEQ * 32 + 255) / 256, 256, 0, stream>>>(tab, pos);

  dim3 gproj(NROWS / 128, DM / 128);
  gemm_bt<1><<<gproj, 256, 0, stream>>>(xb, wqb, (void*)Qb, tab);
  gemm_bt<1><<<gproj, 256, 0, stream>>>(xb, wkb, (void*)Kb, tab);
  gemm_bt<2><<<gproj, 256, 0, stream>>>(xb, wvb, (void*)Vb, nullptr);
  flash_attn<<<dim3(8, NB * NH), 256, 0, stream>>>(Qb, Kb, Vb, AO);
  gemm_bt<0><<<gproj, 256, 0, stream>>>(AO, wob, d_out, nullptr);
}